// Round 1
// baseline (6270.069 us; speedup 1.0000x reference)
//
#include <hip/hip_runtime.h>
#include <math.h>

#define DD 768
#define NH 4
#define HDIM 192
#define BBATCH 8
#define NSEQ 1024
#define TLEN 2000

__device__ __forceinline__ float gelu_f(float x){
  return 0.5f * x * (1.0f + erff(x * 0.70710678118654752440f));
}

__device__ __forceinline__ float wave_sum(float v){
  #pragma unroll
  for (int off = 32; off; off >>= 1) v += __shfl_xor(v, off);
  return v;
}
__device__ __forceinline__ float wave_max(float v){
  #pragma unroll
  for (int off = 32; off; off >>= 1) v = fmaxf(v, __shfl_xor(v, off));
  return v;
}

// ---------------- conv1 (20->128, k=3, pad 1) + bn + gelu ----------------
__global__ __launch_bounds__(256) void k_conv1(const float* __restrict__ cqcc,
    const float* __restrict__ w, const float* __restrict__ bias,
    const float* __restrict__ g, const float* __restrict__ be,
    const float* __restrict__ mm, const float* __restrict__ vv,
    float* __restrict__ out){
  int idx = blockIdx.x * 256 + threadIdx.x;
  if (idx >= BBATCH * 128 * TLEN) return;
  int t = idx % TLEN; int c = (idx / TLEN) % 128; int b = idx / (TLEN * 128);
  float acc = bias[c];
  const float* wp = w + c * 60;
  const float* xp = cqcc + (size_t)b * 20 * TLEN;
  #pragma unroll
  for (int ic = 0; ic < 20; ++ic){
    float xm = (t > 0)        ? xp[ic*TLEN + t - 1] : 0.f;
    float x0 =                  xp[ic*TLEN + t];
    float xq = (t < TLEN - 1) ? xp[ic*TLEN + t + 1] : 0.f;
    acc += wp[ic*3+0]*xm + wp[ic*3+1]*x0 + wp[ic*3+2]*xq;
  }
  acc = (acc - mm[c]) * rsqrtf(vv[c] + 1e-5f) * g[c] + be[c];
  out[idx] = gelu_f(acc);
}

// ---------------- conv2 (128->768, k=3, pad 1) + bn + gelu ----------------
// grid: (2 t-chunks of 256 groups, 768 oc, 8 b); each thread does 4 t.
__global__ __launch_bounds__(256) void k_conv2(const float* __restrict__ x1,
    const float* __restrict__ w, const float* __restrict__ bias,
    const float* __restrict__ g, const float* __restrict__ be,
    const float* __restrict__ mm, const float* __restrict__ vv,
    float* __restrict__ out){
  int grp = blockIdx.x * 256 + threadIdx.x;   // t group (4 t each), 500 groups
  if (grp >= TLEN / 4) return;
  int tb = grp * 4;
  int oc = blockIdx.y, b = blockIdx.z;
  float a0, a1, a2, a3;
  a0 = a1 = a2 = a3 = bias[oc];
  const float* wp = w + oc * 128 * 3;
  const float* xp = x1 + (size_t)b * 128 * TLEN;
  for (int ic = 0; ic < 128; ++ic){
    const float* xr = xp + ic * TLEN;
    float4 xv = *(const float4*)(xr + tb);
    float xm = (tb > 0)            ? xr[tb - 1] : 0.f;
    float xq = (tb + 4 < TLEN)     ? xr[tb + 4] : 0.f;
    float w0 = wp[ic*3+0], w1 = wp[ic*3+1], w2 = wp[ic*3+2];
    a0 += w0*xm   + w1*xv.x + w2*xv.y;
    a1 += w0*xv.x + w1*xv.y + w2*xv.z;
    a2 += w0*xv.y + w1*xv.z + w2*xv.w;
    a3 += w0*xv.z + w1*xv.w + w2*xq;
  }
  float sc = rsqrtf(vv[oc] + 1e-5f) * g[oc];
  float mu = mm[oc], bb = be[oc];
  float4 o;
  o.x = gelu_f((a0 - mu) * sc + bb);
  o.y = gelu_f((a1 - mu) * sc + bb);
  o.z = gelu_f((a2 - mu) * sc + bb);
  o.w = gelu_f((a3 - mu) * sc + bb);
  *(float4*)(out + ((size_t)b * DD + oc) * TLEN + tb) = o;
}

// ---------------- interp (2000 -> 1024 linear) + pos_embed add ----------------
__global__ __launch_bounds__(256) void k_interp(const float* __restrict__ x2,
    const float* __restrict__ pe, float* __restrict__ cq){
  int idx = blockIdx.x * 256 + threadIdx.x;
  if (idx >= BBATCH * NSEQ * DD) return;
  int d = idx % DD; int i = (idx / DD) % NSEQ; int b = idx / (DD * NSEQ);
  float p = (i + 0.5f) * ((float)TLEN / (float)NSEQ) - 0.5f;
  p = fminf(fmaxf(p, 0.f), (float)(TLEN - 1));
  int lo = (int)floorf(p);
  int hi = min(lo + 1, TLEN - 1);
  float w = p - (float)lo;
  const float* xp = x2 + ((size_t)b * DD + d) * TLEN;
  float val = xp[lo] * (1.f - w) + xp[hi] * w;
  cq[idx] = val + pe[(size_t)i * DD + d];
}

__global__ __launch_bounds__(256) void k_addpos(const float* __restrict__ x,
    const float* __restrict__ pe, float* __restrict__ y){
  int idx = blockIdx.x * 256 + threadIdx.x;
  if (idx >= BBATCH * NSEQ * DD) return;
  int d = idx % DD; int i = (idx / DD) % NSEQ;
  y[idx] = x[idx] + pe[(size_t)i * DD + d];
}

__global__ __launch_bounds__(256) void k_add(float* __restrict__ y,
    const float* __restrict__ a){
  int idx = blockIdx.x * 256 + threadIdx.x;
  if (idx >= BBATCH * NSEQ * DD) return;
  y[idx] += a[idx];
}

// ---------------- layernorm over last dim 768 (optional per-batch ctx add) ----
__global__ __launch_bounds__(256) void k_ln(const float* __restrict__ in,
    const float* __restrict__ ctx, const float* __restrict__ g,
    const float* __restrict__ be, float* __restrict__ out){
  __shared__ float ss[4], sqq[4];
  int row = blockIdx.x, tid = threadIdx.x;
  const float* ip = in + (size_t)row * DD;
  int b = row >> 10;
  float v[3]; float s = 0.f, sq = 0.f;
  #pragma unroll
  for (int j = 0; j < 3; ++j){
    int d = j * 256 + tid;
    float x = ip[d];
    if (ctx) x += ctx[b * DD + d];
    v[j] = x; s += x; sq += x * x;
  }
  s = wave_sum(s); sq = wave_sum(sq);
  int w = tid >> 6;
  if ((tid & 63) == 0){ ss[w] = s; sqq[w] = sq; }
  __syncthreads();
  s  = ss[0] + ss[1] + ss[2] + ss[3];
  sq = sqq[0] + sqq[1] + sqq[2] + sqq[3];
  float mean = s * (1.f / DD);
  float var  = sq * (1.f / DD) - mean * mean;
  float r = rsqrtf(var + 1e-5f);
  #pragma unroll
  for (int j = 0; j < 3; ++j){
    int d = j * 256 + tid;
    out[(size_t)row * DD + d] = (v[j] - mean) * r * g[d] + be[d];
  }
}

// ---------------- fp32 GEMM: C[M,N] = A[M,K] @ W[N,K]^T + bias[N] ------------
__global__ __launch_bounds__(256) void k_gemm(const float* __restrict__ A,
    const float* __restrict__ W, const float* __restrict__ bias,
    float* __restrict__ C, int M, int N, int K){
  __shared__ float As[16][64];
  __shared__ float Bs[16][64];
  const int tid = threadIdx.x;
  const int n0 = blockIdx.x * 64, m0 = blockIdx.y * 64;
  const int tx = tid & 15, ty = tid >> 4;
  const int lm = tid >> 2, lk = (tid & 3) * 4;
  float acc[4][4] = {};
  const float* Ap = A + (size_t)(m0 + lm) * K + lk;
  const float* Wp = W + (size_t)(n0 + lm) * K + lk;
  for (int k0 = 0; k0 < K; k0 += 16){
    float4 a  = *(const float4*)(Ap + k0);
    float4 bv = *(const float4*)(Wp + k0);
    As[lk+0][lm] = a.x;  As[lk+1][lm] = a.y;  As[lk+2][lm] = a.z;  As[lk+3][lm] = a.w;
    Bs[lk+0][lm] = bv.x; Bs[lk+1][lm] = bv.y; Bs[lk+2][lm] = bv.z; Bs[lk+3][lm] = bv.w;
    __syncthreads();
    #pragma unroll
    for (int k = 0; k < 16; ++k){
      const float4 av = *(const float4*)&As[k][ty*4];
      const float4 bw = *(const float4*)&Bs[k][tx*4];
      acc[0][0] += av.x*bw.x; acc[0][1] += av.x*bw.y; acc[0][2] += av.x*bw.z; acc[0][3] += av.x*bw.w;
      acc[1][0] += av.y*bw.x; acc[1][1] += av.y*bw.y; acc[1][2] += av.y*bw.z; acc[1][3] += av.y*bw.w;
      acc[2][0] += av.z*bw.x; acc[2][1] += av.z*bw.y; acc[2][2] += av.z*bw.z; acc[2][3] += av.z*bw.w;
      acc[3][0] += av.w*bw.x; acc[3][1] += av.w*bw.y; acc[3][2] += av.w*bw.z; acc[3][3] += av.w*bw.w;
    }
    __syncthreads();
  }
  const int cn = n0 + tx * 4;
  float b0 = bias[cn+0], b1 = bias[cn+1], b2 = bias[cn+2], b3 = bias[cn+3];
  #pragma unroll
  for (int i = 0; i < 4; ++i){
    float4 o;
    o.x = acc[i][0] + b0; o.y = acc[i][1] + b1; o.z = acc[i][2] + b2; o.w = acc[i][3] + b3;
    *(float4*)(C + (size_t)(m0 + ty*4 + i) * N + cn) = o;
  }
}

// ---------------- flash attention fp32: BQ=32, BK=32, HD=192 ------------------
// grid (32 qchunks, 4 heads, 8 batch), 256 threads.
__global__ __launch_bounds__(256) void k_attn(const float* __restrict__ Q,
    const float* __restrict__ Kx, const float* __restrict__ Vx,
    float* __restrict__ Optr){
  __shared__ float Qt[HDIM * 34];       // [d][q], pitch 34
  __shared__ float KV[HDIM * 34];       // Kt [d][k] pitch 34 | Vs [k][d] pitch 192
  __shared__ float Pl[32 * 34];         // [k][q], pitch 34
  __shared__ float m_s[32], l_s[32], c_s[32];
  const int tid = threadIdx.x;
  const int qc = blockIdx.x, h = blockIdx.y, b = blockIdx.z;
  const size_t base = (size_t)b * NSEQ * DD + h * HDIM;
  const int q0 = qc * 32;
  #pragma unroll
  for (int j = 0; j < 24; ++j){
    int idx = tid + j * 256;            // 6144 = 32*192
    int q = idx / HDIM, d = idx % HDIM;
    Qt[d * 34 + q] = Q[base + (size_t)(q0 + q) * DD + d];
  }
  if (tid < 32){ m_s[tid] = -1e30f; l_s[tid] = 0.f; }
  float o[2][12] = {};
  const int qp = tid & 15, dblk = tid >> 4;
  const int sq = (tid & 15) * 2, sk = (tid >> 4) * 2;
  const float scale = 0.07216878364870322f;  // 1/sqrt(192)
  for (int kt = 0; kt < 32; ++kt){
    __syncthreads();                    // prev PV done; Qt ready (iter 0)
    #pragma unroll
    for (int j = 0; j < 24; ++j){
      int idx = tid + j * 256;
      int k = idx / HDIM, d = idx % HDIM;
      KV[d * 34 + k] = Kx[base + (size_t)(kt * 32 + k) * DD + d];
    }
    __syncthreads();                    // Kt ready
    float s00 = 0, s01 = 0, s10 = 0, s11 = 0;
    for (int d = 0; d < HDIM; ++d){
      float2 qv = *(const float2*)&Qt[d * 34 + sq];
      float2 kv = *(const float2*)&KV[d * 34 + sk];
      s00 += qv.x * kv.x; s01 += qv.x * kv.y;
      s10 += qv.y * kv.x; s11 += qv.y * kv.y;
    }
    Pl[(sk+0) * 34 + sq + 0] = s00 * scale;
    Pl[(sk+1) * 34 + sq + 0] = s01 * scale;
    Pl[(sk+0) * 34 + sq + 1] = s10 * scale;
    Pl[(sk+1) * 34 + sq + 1] = s11 * scale;
    __syncthreads();                    // P ready, Kt reads done
    {
      int q = tid >> 3, sub = tid & 7;
      float pv[4]; float pm = -1e30f;
      #pragma unroll
      for (int j = 0; j < 4; ++j){ pv[j] = Pl[(sub*4+j) * 34 + q]; pm = fmaxf(pm, pv[j]); }
      #pragma unroll
      for (int off = 1; off < 8; off <<= 1) pm = fmaxf(pm, __shfl_xor(pm, off));
      float m_old = m_s[q];
      float m_new = fmaxf(m_old, pm);
      float c = __expf(m_old - m_new);
      float psum = 0.f;
      #pragma unroll
      for (int j = 0; j < 4; ++j){
        float p = __expf(pv[j] - m_new);
        Pl[(sub*4+j) * 34 + q] = p;
        psum += p;
      }
      #pragma unroll
      for (int off = 1; off < 8; off <<= 1) psum += __shfl_xor(psum, off);
      if (sub == 0){ m_s[q] = m_new; l_s[q] = l_s[q] * c + psum; c_s[q] = c; }
    }
    __syncthreads();                    // stats/P final
    #pragma unroll
    for (int j = 0; j < 24; ++j){
      int idx = tid + j * 256;
      int k = idx / HDIM, d = idx % HDIM;
      KV[k * HDIM + d] = Vx[base + (size_t)(kt * 32 + k) * DD + d];
    }
    {
      float c0 = c_s[qp*2 + 0], c1 = c_s[qp*2 + 1];
      #pragma unroll
      for (int j = 0; j < 12; ++j){ o[0][j] *= c0; o[1][j] *= c1; }
    }
    __syncthreads();                    // Vs ready
    for (int k = 0; k < 32; ++k){
      float2 pp = *(const float2*)&Pl[k * 34 + qp * 2];
      const float4* vp4 = (const float4*)&KV[k * HDIM + dblk * 12];
      float4 v0 = vp4[0], v1 = vp4[1], v2 = vp4[2];
      float vv[12];
      *(float4*)&vv[0] = v0; *(float4*)&vv[4] = v1; *(float4*)&vv[8] = v2;
      #pragma unroll
      for (int j = 0; j < 12; ++j){ o[0][j] += pp.x * vv[j]; o[1][j] += pp.y * vv[j]; }
    }
  }
  const float i0 = 1.0f / l_s[qp*2 + 0];
  const float i1 = 1.0f / l_s[qp*2 + 1];
  float* op0 = Optr + base + (size_t)(q0 + qp*2 + 0) * DD + dblk * 12;
  float* op1 = Optr + base + (size_t)(q0 + qp*2 + 1) * DD + dblk * 12;
  #pragma unroll
  for (int c = 0; c < 3; ++c){
    float4 f0, f1;
    f0.x = o[0][c*4+0]*i0; f0.y = o[0][c*4+1]*i0; f0.z = o[0][c*4+2]*i0; f0.w = o[0][c*4+3]*i0;
    f1.x = o[1][c*4+0]*i1; f1.y = o[1][c*4+1]*i1; f1.z = o[1][c*4+2]*i1; f1.w = o[1][c*4+3]*i1;
    *(float4*)(op0 + c*4) = f0;
    *(float4*)(op1 + c*4) = f1;
  }
}

// ---------------- GAT helpers ----------------
__global__ __launch_bounds__(256) void k_rowdot(const float* __restrict__ h,
    const float* __restrict__ aw, float* __restrict__ sj){
  __shared__ float red[4];
  int row = blockIdx.x, tid = threadIdx.x;
  const float* hp = h + (size_t)row * DD;
  float s = 0.f;
  #pragma unroll
  for (int j = 0; j < 3; ++j){ int d = j * 256 + tid; s += hp[d] * aw[d]; }
  s = wave_sum(s);
  if ((tid & 63) == 0) red[tid >> 6] = s;
  __syncthreads();
  if (tid == 0) sj[row] = red[0] + red[1] + red[2] + red[3];
}

__global__ __launch_bounds__(256) void k_softmax1024(const float* __restrict__ x,
    float* __restrict__ y){
  __shared__ float red[4];
  int b = blockIdx.x, tid = threadIdx.x;
  const float* ip = x + b * NSEQ;
  float v[4]; float mx = -1e30f;
  #pragma unroll
  for (int j = 0; j < 4; ++j){ v[j] = ip[j * 256 + tid]; mx = fmaxf(mx, v[j]); }
  mx = wave_max(mx);
  if ((tid & 63) == 0) red[tid >> 6] = mx;
  __syncthreads();
  mx = fmaxf(fmaxf(red[0], red[1]), fmaxf(red[2], red[3]));
  __syncthreads();
  float s = 0.f;
  #pragma unroll
  for (int j = 0; j < 4; ++j){ v[j] = __expf(v[j] - mx); s += v[j]; }
  s = wave_sum(s);
  if ((tid & 63) == 0) red[tid >> 6] = s;
  __syncthreads();
  s = red[0] + red[1] + red[2] + red[3];
  float inv = 1.0f / s;
  #pragma unroll
  for (int j = 0; j < 4; ++j) y[b * NSEQ + j * 256 + tid] = v[j] * inv;
}

__global__ __launch_bounds__(256) void k_ctx(const float* __restrict__ alpha,
    const float* __restrict__ h, float* __restrict__ ctx){
  int d = blockIdx.x * 256 + threadIdx.x;   // 768 -> 3 blocks
  int b = blockIdx.y;
  if (d >= DD) return;
  float acc = 0.f;
  const float* hp = h + (size_t)b * NSEQ * DD + d;
  const float* ap = alpha + b * NSEQ;
  for (int j = 0; j < NSEQ; ++j) acc += ap[j] * hp[(size_t)j * DD];
  ctx[b * DD + d] = acc;
}

// ---------------- pooling + classifier ----------------
__global__ __launch_bounds__(256) void k_pool(const float* __restrict__ x,
    float* __restrict__ pooled){
  int d = blockIdx.x * 256 + threadIdx.x;
  int b = blockIdx.y;
  if (d >= DD) return;
  float acc = 0.f;
  const float* xp = x + (size_t)b * NSEQ * DD + d;
  for (int i = 0; i < NSEQ; ++i) acc += xp[(size_t)i * DD];
  pooled[b * DD + d] = acc * (1.0f / NSEQ);
}

__global__ __launch_bounds__(128) void k_clf(const float* __restrict__ pooled,
    const float* __restrict__ w1, const float* __restrict__ b1,
    const float* __restrict__ w2, const float* __restrict__ b2,
    float* __restrict__ out){
  __shared__ float pl[DD];
  __shared__ float h1[128];
  int b = blockIdx.x, tid = threadIdx.x;
  #pragma unroll
  for (int j = 0; j < 6; ++j) pl[j * 128 + tid] = pooled[b * DD + j * 128 + tid];
  __syncthreads();
  float acc = b1[tid];
  const float* wp = w1 + (size_t)tid * DD;
  for (int d = 0; d < DD; ++d) acc += pl[d] * wp[d];
  h1[tid] = gelu_f(acc);
  __syncthreads();
  if (tid < 2){
    float o = b2[tid];
    const float* w2p = w2 + tid * 128;
    for (int c = 0; c < 128; ++c) o += h1[c] * w2p[c];
    out[b * 2 + tid] = o;
  }
}

// =========================== launcher ===========================
extern "C" void kernel_launch(void* const* d_in, const int* in_sizes, int n_in,
                              void* d_out, int out_size, void* d_ws, size_t ws_size,
                              hipStream_t stream){
  (void)in_sizes; (void)n_in; (void)out_size;
  const float* w2v      = (const float*)d_in[0];
  const float* cqcc     = (const float*)d_in[1];
  const float* conv1_w  = (const float*)d_in[2];
  const float* conv1_b  = (const float*)d_in[3];
  const float* bn1_g    = (const float*)d_in[4];
  const float* bn1_b    = (const float*)d_in[5];
  const float* bn1_m    = (const float*)d_in[6];
  const float* bn1_v    = (const float*)d_in[7];
  const float* conv2_w  = (const float*)d_in[8];
  const float* conv2_b  = (const float*)d_in[9];
  const float* bn2_g    = (const float*)d_in[10];
  const float* bn2_b    = (const float*)d_in[11];
  const float* bn2_m    = (const float*)d_in[12];
  const float* bn2_v    = (const float*)d_in[13];
  const float* pos_embed= (const float*)d_in[14];
  const float* lnq_g    = (const float*)d_in[15];
  const float* lnq_b    = (const float*)d_in[16];
  const float* lnkv_g   = (const float*)d_in[17];
  const float* lnkv_b   = (const float*)d_in[18];
  const float* a1_in_w  = (const float*)d_in[19];
  const float* a1_in_b  = (const float*)d_in[20];
  const float* a1_out_w = (const float*)d_in[21];
  const float* a1_out_b = (const float*)d_in[22];
  const float* a2_in_w  = (const float*)d_in[23];
  const float* a2_in_b  = (const float*)d_in[24];
  const float* a2_out_w = (const float*)d_in[25];
  const float* a2_out_b = (const float*)d_in[26];
  const float* gat_fc_w = (const float*)d_in[27];
  const float* gat_fc_b = (const float*)d_in[28];
  const float* gat_a_w  = (const float*)d_in[29];
  // d_in[30] gat_a_b: cancels in softmax over j (constant per row) — unused.
  const float* gln_g    = (const float*)d_in[31];
  const float* gln_b    = (const float*)d_in[32];
  const float* clf_w1   = (const float*)d_in[33];
  const float* clf_b1   = (const float*)d_in[34];
  const float* clf_w2   = (const float*)d_in[35];
  const float* clf_b2   = (const float*)d_in[36];

  float* ws = (float*)d_ws;
  const size_t S = (size_t)BBATCH * NSEQ * DD;   // 6,291,456 floats
  if (ws_size < (9 * S + 32768) * sizeof(float)) return;  // need ~217 MB

  float* cq   = ws;              // slot 0
  float* wpl  = ws + 1*S;        // slot 1: w2v + pos
  float* t2   = ws + 2*S;        // slot 2: lnA / attention out
  float* t3   = ws + 3*S;        // slot 3: lnB
  float* Qb   = ws + 4*S;        // slot 4: Q / x1 / gat h
  float* Kb   = ws + 5*S;        // slot 5: K / x2 (spans 5+6)
  float* Vb   = ws + 6*S;        // slot 6: V
  float* o1   = ws + 7*S;        // slot 7: out1
  float* xb   = ws + 8*S;        // slot 8: out2 -> x
  float* smal = ws + 9*S;
  float* sj     = smal;          // 8192
  float* alpha  = smal + 8192;   // 8192
  float* ctx    = smal + 16384;  // 6144
  float* pooled = smal + 22528;  // 6144
  float* x1 = Qb;                // 2,048,000 floats  (< S)
  float* x2 = Kb;                // 12,288,000 floats (< 2S)

  const int EW = (int)((S + 255) / 256);

  k_conv1<<<(BBATCH*128*TLEN + 255)/256, 256, 0, stream>>>(cqcc, conv1_w, conv1_b,
      bn1_g, bn1_b, bn1_m, bn1_v, x1);
  k_conv2<<<dim3(2, DD, BBATCH), 256, 0, stream>>>(x1, conv2_w, conv2_b,
      bn2_g, bn2_b, bn2_m, bn2_v, x2);
  k_interp<<<EW, 256, 0, stream>>>(x2, pos_embed, cq);
  k_addpos<<<EW, 256, 0, stream>>>(w2v, pos_embed, wpl);

  dim3 gg(DD/64, (BBATCH*NSEQ)/64);   // (12, 128)
  dim3 ga(NSEQ/32, NH, BBATCH);       // (32, 4, 8)

  // MHA1: q = LNq(cq), kv = LNkv(w)
  k_ln<<<BBATCH*NSEQ, 256, 0, stream>>>(cq,  nullptr, lnq_g,  lnq_b,  t2);
  k_ln<<<BBATCH*NSEQ, 256, 0, stream>>>(wpl, nullptr, lnkv_g, lnkv_b, t3);
  k_gemm<<<gg, 256, 0, stream>>>(t2, a1_in_w,            a1_in_b,        Qb, BBATCH*NSEQ, DD, DD);
  k_gemm<<<gg, 256, 0, stream>>>(t3, a1_in_w + DD*DD,    a1_in_b + DD,   Kb, BBATCH*NSEQ, DD, DD);
  k_gemm<<<gg, 256, 0, stream>>>(t3, a1_in_w + 2*DD*DD,  a1_in_b + 2*DD, Vb, BBATCH*NSEQ, DD, DD);
  k_attn<<<ga, 256, 0, stream>>>(Qb, Kb, Vb, t2);
  k_gemm<<<gg, 256, 0, stream>>>(t2, a1_out_w, a1_out_b, o1, BBATCH*NSEQ, DD, DD);

  // MHA2: q = LNq(w), kv = LNkv(cq)
  k_ln<<<BBATCH*NSEQ, 256, 0, stream>>>(wpl, nullptr, lnq_g,  lnq_b,  t2);
  k_ln<<<BBATCH*NSEQ, 256, 0, stream>>>(cq,  nullptr, lnkv_g, lnkv_b, t3);
  k_gemm<<<gg, 256, 0, stream>>>(t2, a2_in_w,            a2_in_b,        Qb, BBATCH*NSEQ, DD, DD);
  k_gemm<<<gg, 256, 0, stream>>>(t3, a2_in_w + DD*DD,    a2_in_b + DD,   Kb, BBATCH*NSEQ, DD, DD);
  k_gemm<<<gg, 256, 0, stream>>>(t3, a2_in_w + 2*DD*DD,  a2_in_b + 2*DD, Vb, BBATCH*NSEQ, DD, DD);
  k_attn<<<ga, 256, 0, stream>>>(Qb, Kb, Vb, t2);
  k_gemm<<<gg, 256, 0, stream>>>(t2, a2_out_w, a2_out_b, xb, BBATCH*NSEQ, DD, DD);
  k_add<<<EW, 256, 0, stream>>>(xb, o1);   // x = out1 + out2

  // GAT x3 (softmax over j collapses: alpha independent of i)
  for (int l = 0; l < 3; ++l){
    k_gemm<<<gg, 256, 0, stream>>>(xb, gat_fc_w + (size_t)l*DD*DD, gat_fc_b + l*DD,
                                   Qb, BBATCH*NSEQ, DD, DD);
    k_rowdot<<<BBATCH*NSEQ, 256, 0, stream>>>(Qb, gat_a_w + l*2*DD + DD, sj);
    k_softmax1024<<<BBATCH, 256, 0, stream>>>(sj, alpha);
    k_ctx<<<dim3(3, BBATCH), 256, 0, stream>>>(alpha, Qb, ctx);
    k_ln<<<BBATCH*NSEQ, 256, 0, stream>>>(xb, ctx, gln_g + l*DD, gln_b + l*DD, xb);
  }

  k_pool<<<dim3(3, BBATCH), 256, 0, stream>>>(xb, pooled);
  k_clf<<<BBATCH, 128, 0, stream>>>(pooled, clf_w1, clf_b1, clf_w2, clf_b2,
                                    (float*)d_out);
}

// Round 2
// 1240.298 us; speedup vs baseline: 5.0553x; 5.0553x over previous
//
#include <hip/hip_runtime.h>
#include <math.h>

#define DD 768
#define NH 4
#define HDIM 192
#define BBATCH 8
#define NSEQ 1024
#define TLEN 2000

typedef _Float16 h16;
typedef _Float16 half8v __attribute__((ext_vector_type(8)));
typedef _Float16 half4v __attribute__((ext_vector_type(4)));
typedef float f32x4 __attribute__((ext_vector_type(4)));

__device__ __forceinline__ float gelu_f(float x){
  return 0.5f * x * (1.0f + erff(x * 0.70710678118654752440f));
}
__device__ __forceinline__ float wave_sum(float v){
  #pragma unroll
  for (int off = 32; off; off >>= 1) v += __shfl_xor(v, off);
  return v;
}
__device__ __forceinline__ float wave_max(float v){
  #pragma unroll
  for (int off = 32; off; off >>= 1) v = fmaxf(v, __shfl_xor(v, off));
  return v;
}

// ---------------- f32 -> f16 cast ----------------
__global__ __launch_bounds__(256) void k_cast(const float* __restrict__ s,
    h16* __restrict__ d, int n){
  int i = blockIdx.x * 256 + threadIdx.x;
  if (i < n) d[i] = (h16)s[i];
}

// ---------------- conv1 (20->128, k=3) + bn + gelu, LDS tiled ----------------
__global__ __launch_bounds__(256) void k_conv1t(const float* __restrict__ cqcc,
    const float* __restrict__ w, const float* __restrict__ bias,
    const float* __restrict__ g, const float* __restrict__ be,
    const float* __restrict__ mm, const float* __restrict__ vv,
    float* __restrict__ out){
  __shared__ float xs[20][258];
  __shared__ float wsm[32*60];
  const int t0 = blockIdx.x * 256;
  const int ocg = blockIdx.y, b = blockIdx.z;
  const int tid = threadIdx.x;
  for (int idx = tid; idx < 20*258; idx += 256){
    int ic = idx / 258, tt = idx % 258;
    int t = t0 + tt - 1;
    xs[ic][tt] = (t >= 0 && t < TLEN) ? cqcc[((size_t)b*20 + ic)*TLEN + t] : 0.f;
  }
  for (int idx = tid; idx < 32*60; idx += 256)
    wsm[idx] = w[ocg*32*60 + idx];
  __syncthreads();
  int t = t0 + tid;
  if (t >= TLEN) return;
  float acc[32] = {};
  for (int ic = 0; ic < 20; ++ic){
    float x0 = xs[ic][tid], x1v = xs[ic][tid+1], x2v = xs[ic][tid+2];
    #pragma unroll
    for (int oc = 0; oc < 32; ++oc){
      const float* wp = &wsm[(oc*20 + ic)*3];
      acc[oc] += wp[0]*x0 + wp[1]*x1v + wp[2]*x2v;
    }
  }
  #pragma unroll 4
  for (int oc = 0; oc < 32; ++oc){
    int c = ocg*32 + oc;
    float s = rsqrtf(vv[c] + 1e-5f) * g[c];
    float val = (acc[oc] + bias[c] - mm[c]) * s + be[c];
    out[((size_t)b*128 + c)*TLEN + t] = gelu_f(val);
  }
}

// ---------------- im2col for conv2: x1[b][128][2000] -> A2[16000][384] f16 ---
__global__ __launch_bounds__(256) void k_im2col(const float* __restrict__ x1,
    h16* __restrict__ A2){
  int idx = blockIdx.x * 256 + threadIdx.x;
  if (idx >= 16000*384) return;
  int c = idx % 384, m = idx / 384;
  int b = m / TLEN, t = m % TLEN;
  int ic = c / 3, kh = c % 3;
  int ts = t + kh - 1;
  float v = (ts < 0 || ts >= TLEN) ? 0.f : x1[((size_t)b*128 + ic)*TLEN + ts];
  A2[idx] = (h16)v;
}

// ---------------- BN epilogue constants for conv2 ----------------
__global__ void k_bnprep(const float* __restrict__ cb, const float* __restrict__ g,
    const float* __restrict__ be, const float* __restrict__ m,
    const float* __restrict__ v, float* __restrict__ sc, float* __restrict__ off){
  int i = blockIdx.x * 256 + threadIdx.x;
  if (i >= DD) return;
  float s = g[i] * rsqrtf(v[i] + 1e-5f);
  sc[i] = s;
  off[i] = (cb[i] - m[i]) * s + be[i];
}

// ---------------- interp (2000->1024) on [b][t][768] layout + pos ----------
__global__ __launch_bounds__(256) void k_interp2(const float* __restrict__ x2,
    const float* __restrict__ pe, float* __restrict__ cq){
  int idx = blockIdx.x * 256 + threadIdx.x;
  if (idx >= BBATCH * NSEQ * DD) return;
  int d = idx % DD; int i = (idx / DD) % NSEQ; int b = idx / (DD * NSEQ);
  float p = (i + 0.5f) * ((float)TLEN / (float)NSEQ) - 0.5f;
  p = fminf(fmaxf(p, 0.f), (float)(TLEN - 1));
  int lo = (int)floorf(p);
  int hi = min(lo + 1, TLEN - 1);
  float w = p - (float)lo;
  const float* base = x2 + (size_t)b * TLEN * DD + d;
  float val = base[(size_t)lo * DD] * (1.f - w) + base[(size_t)hi * DD] * w;
  cq[idx] = val + pe[(size_t)i * DD + d];
}

__global__ __launch_bounds__(256) void k_addpos(const float* __restrict__ x,
    const float* __restrict__ pe, float* __restrict__ y){
  int idx = blockIdx.x * 256 + threadIdx.x;
  if (idx >= BBATCH * NSEQ * DD) return;
  int d = idx % DD; int i = (idx / DD) % NSEQ;
  y[idx] = x[idx] + pe[(size_t)i * DD + d];
}

// ---------------- layernorm 768, optional ctx add, dual outputs ----------
__global__ __launch_bounds__(256) void k_ln2(const float* __restrict__ in,
    const float* __restrict__ ctx, const float* __restrict__ g,
    const float* __restrict__ be, float* __restrict__ outf, h16* __restrict__ outh){
  __shared__ float ss[4], sqq[4];
  int row = blockIdx.x, tid = threadIdx.x;
  const float* ip = in + (size_t)row * DD;
  int b = row >> 10;
  float v[3]; float s = 0.f, sq = 0.f;
  #pragma unroll
  for (int j = 0; j < 3; ++j){
    int d = j * 256 + tid;
    float x = ip[d];
    if (ctx) x += ctx[b * DD + d];
    v[j] = x; s += x; sq += x * x;
  }
  s = wave_sum(s); sq = wave_sum(sq);
  int w = tid >> 6;
  if ((tid & 63) == 0){ ss[w] = s; sqq[w] = sq; }
  __syncthreads();
  s  = ss[0] + ss[1] + ss[2] + ss[3];
  sq = sqq[0] + sqq[1] + sqq[2] + sqq[3];
  float mean = s * (1.f / DD);
  float var  = sq * (1.f / DD) - mean * mean;
  float r = rsqrtf(var + 1e-5f);
  #pragma unroll
  for (int j = 0; j < 3; ++j){
    int d = j * 256 + tid;
    float y = (v[j] - mean) * r * g[d] + be[d];
    if (outf) outf[(size_t)row * DD + d] = y;
    if (outh) outh[(size_t)row * DD + d] = (h16)y;
  }
}

// ---------------- f16 MFMA GEMM: C[M,N] = A[M,K] @ W[N,K]^T ------------------
// BM=128, BK=32, 4 waves (2x2), wave tile 64 x BN/2. Batched via z-decode:
// base = (z>>2)*s_hi + (z&3)*s_lo.
template<int BN>
__global__ __launch_bounds__(256) void k_gemm_h(
    const h16* __restrict__ A, const h16* __restrict__ W,
    long long sA_hi, long long sA_lo, long long sW_hi, long long sW_lo,
    long long sC_hi, long long sC_lo,
    int lda, int ldw, int ldc, int K,
    const float* __restrict__ bias, const float* __restrict__ sc,
    const float* __restrict__ off,
    const h16* __restrict__ addh, float* __restrict__ outf, h16* __restrict__ outh)
{
  __shared__ h16 Als[128*40];
  __shared__ h16 Bls[BN*40];
  const int tid = threadIdx.x;
  const int z = blockIdx.z, zh = z >> 2, zl = z & 3;
  const size_t aBase = (size_t)(zh * sA_hi + zl * sA_lo);
  const size_t wBase = (size_t)(zh * sW_hi + zl * sW_lo);
  const size_t cBase = (size_t)(zh * sC_hi + zl * sC_lo);
  const int n0 = blockIdx.x * BN, m0 = blockIdx.y * 128;
  const int lane = tid & 63, wid = tid >> 6;
  const int wr = wid >> 1, wc = wid & 1;
  const int lr = lane & 15, lg = lane >> 4;
  constexpr int NR = BN / 32;
  f32x4 acc[4][NR] = {};
  const h16* Ab = A + aBase;
  const h16* Wb = W + wBase;
  for (int kt = 0; kt < K; kt += 32){
    __syncthreads();
    #pragma unroll
    for (int i = 0; i < 2; ++i){
      int c = tid + i*256;
      int row = c >> 2, gch = c & 3;
      *(half8v*)&Als[row*40 + gch*8] =
        *(const half8v*)(Ab + (size_t)(m0+row)*lda + kt + gch*8);
    }
    #pragma unroll
    for (int i = 0; i < BN/64; ++i){
      int c = tid + i*256;
      int row = c >> 2, gch = c & 3;
      *(half8v*)&Bls[row*40 + gch*8] =
        *(const half8v*)(Wb + (size_t)(n0+row)*ldw + kt + gch*8);
    }
    __syncthreads();
    half8v af[4], bf[NR];
    #pragma unroll
    for (int mi = 0; mi < 4; ++mi)
      af[mi] = *(const half8v*)&Als[(wr*64 + mi*16 + lr)*40 + lg*8];
    #pragma unroll
    for (int ni = 0; ni < NR; ++ni)
      bf[ni] = *(const half8v*)&Bls[(wc*(BN/2) + ni*16 + lr)*40 + lg*8];
    #pragma unroll
    for (int mi = 0; mi < 4; ++mi)
      #pragma unroll
      for (int ni = 0; ni < NR; ++ni)
        acc[mi][ni] = __builtin_amdgcn_mfma_f32_16x16x32_f16(af[mi], bf[ni], acc[mi][ni], 0, 0, 0);
  }
  #pragma unroll
  for (int mi = 0; mi < 4; ++mi){
    #pragma unroll
    for (int ni = 0; ni < NR; ++ni){
      int col = n0 + wc*(BN/2) + ni*16 + lr;
      int rowb = m0 + wr*64 + mi*16 + lg*4;
      float cb = bias ? bias[col] : 0.f;
      #pragma unroll
      for (int r = 0; r < 4; ++r){
        int row = rowb + r;
        size_t idx = cBase + (size_t)row * ldc + col;
        float v = acc[mi][ni][r];
        if (sc){ v = v * sc[col] + off[col]; v = gelu_f(v); }
        else v += cb;
        if (addh) v += (float)addh[idx];
        if (outf) outf[idx] = v;
        if (outh) outh[idx] = (h16)v;
      }
    }
  }
}

// ---------------- V transpose: Vh[b][q][h*192+d] -> VT[bh][d][q] -------------
__global__ __launch_bounds__(256) void k_trV(const h16* __restrict__ Vh,
    h16* __restrict__ VT){
  __shared__ h16 tile[32][36];
  const int z = blockIdx.z, b = z >> 2, h = z & 3;
  const int q0 = blockIdx.x * 32, d0 = blockIdx.y * 32;
  const int t = threadIdx.x;
  {
    int qq = t >> 3, dg = (t & 7) * 4;
    const h16* src = Vh + (size_t)b*NSEQ*DD + h*HDIM + (size_t)(q0+qq)*DD + d0 + dg;
    half4v v = *(const half4v*)src;
    *(half4v*)&tile[qq][dg] = v;
  }
  __syncthreads();
  {
    int dd = t >> 3, qg = (t & 7) * 4;
    half4v ov;
    ov[0] = tile[qg+0][dd]; ov[1] = tile[qg+1][dd];
    ov[2] = tile[qg+2][dd]; ov[3] = tile[qg+3][dd];
    *(half4v*)(VT + (size_t)z*HDIM*NSEQ + (size_t)(d0+dd)*NSEQ + q0 + qg) = ov;
  }
}

// ---------------- softmax over S rows (in place, scale fused) ----------------
__global__ __launch_bounds__(256) void k_softmax_s(h16* __restrict__ S){
  __shared__ float red[4];
  const float SCALE = 0.07216878364870322f;  // 1/sqrt(192)
  int row = blockIdx.x, tid = threadIdx.x;
  h16* p = S + (size_t)row * 1024;
  float v[4]; float mx = -1e30f;
  #pragma unroll
  for (int j = 0; j < 4; ++j){ v[j] = (float)p[j*256 + tid] * SCALE; mx = fmaxf(mx, v[j]); }
  mx = wave_max(mx);
  if ((tid & 63) == 0) red[tid >> 6] = mx;
  __syncthreads();
  mx = fmaxf(fmaxf(red[0], red[1]), fmaxf(red[2], red[3]));
  __syncthreads();
  float s = 0.f;
  #pragma unroll
  for (int j = 0; j < 4; ++j){ v[j] = __expf(v[j] - mx); s += v[j]; }
  s = wave_sum(s);
  if ((tid & 63) == 0) red[tid >> 6] = s;
  __syncthreads();
  s = red[0] + red[1] + red[2] + red[3];
  float inv = 1.0f / s;
  #pragma unroll
  for (int j = 0; j < 4; ++j) p[j*256 + tid] = (h16)(v[j] * inv);
}

// ---------------- GAT helpers ----------------
__global__ __launch_bounds__(256) void k_rowdot(const h16* __restrict__ h,
    const float* __restrict__ aw, float* __restrict__ sj){
  __shared__ float red[4];
  int row = blockIdx.x, tid = threadIdx.x;
  const h16* hp = h + (size_t)row * DD;
  float s = 0.f;
  #pragma unroll
  for (int j = 0; j < 3; ++j){ int d = j * 256 + tid; s += (float)hp[d] * aw[d]; }
  s = wave_sum(s);
  if ((tid & 63) == 0) red[tid >> 6] = s;
  __syncthreads();
  if (tid == 0) sj[row] = red[0] + red[1] + red[2] + red[3];
}

__global__ __launch_bounds__(256) void k_softmax1024(const float* __restrict__ x,
    float* __restrict__ y){
  __shared__ float red[4];
  int b = blockIdx.x, tid = threadIdx.x;
  const float* ip = x + b * NSEQ;
  float v[4]; float mx = -1e30f;
  #pragma unroll
  for (int j = 0; j < 4; ++j){ v[j] = ip[j * 256 + tid]; mx = fmaxf(mx, v[j]); }
  mx = wave_max(mx);
  if ((tid & 63) == 0) red[tid >> 6] = mx;
  __syncthreads();
  mx = fmaxf(fmaxf(red[0], red[1]), fmaxf(red[2], red[3]));
  __syncthreads();
  float s = 0.f;
  #pragma unroll
  for (int j = 0; j < 4; ++j){ v[j] = __expf(v[j] - mx); s += v[j]; }
  s = wave_sum(s);
  if ((tid & 63) == 0) red[tid >> 6] = s;
  __syncthreads();
  s = red[0] + red[1] + red[2] + red[3];
  float inv = 1.0f / s;
  #pragma unroll
  for (int j = 0; j < 4; ++j) y[b * NSEQ + j * 256 + tid] = v[j] * inv;
}

__global__ __launch_bounds__(256) void k_ctx(const float* __restrict__ alpha,
    const h16* __restrict__ h, float* __restrict__ ctx){
  int d = blockIdx.x * 256 + threadIdx.x;
  int b = blockIdx.y;
  if (d >= DD) return;
  float acc = 0.f;
  const h16* hp = h + (size_t)b * NSEQ * DD + d;
  const float* ap = alpha + b * NSEQ;
  for (int j = 0; j < NSEQ; ++j) acc += ap[j] * (float)hp[(size_t)j * DD];
  ctx[b * DD + d] = acc;
}

// ---------------- pooling + classifier ----------------
__global__ __launch_bounds__(256) void k_pool(const float* __restrict__ x,
    float* __restrict__ pooled){
  int d = blockIdx.x * 256 + threadIdx.x;
  int b = blockIdx.y;
  if (d >= DD) return;
  float acc = 0.f;
  const float* xp = x + (size_t)b * NSEQ * DD + d;
  for (int i = 0; i < NSEQ; ++i) acc += xp[(size_t)i * DD];
  pooled[b * DD + d] = acc * (1.0f / NSEQ);
}

__global__ __launch_bounds__(128) void k_clf(const float* __restrict__ pooled,
    const float* __restrict__ w1, const float* __restrict__ b1,
    const float* __restrict__ w2, const float* __restrict__ b2,
    float* __restrict__ out){
  __shared__ float pl[DD];
  __shared__ float h1[128];
  int b = blockIdx.x, tid = threadIdx.x;
  #pragma unroll
  for (int j = 0; j < 6; ++j) pl[j * 128 + tid] = pooled[b * DD + j * 128 + tid];
  __syncthreads();
  float acc = b1[tid];
  const float* wp = w1 + (size_t)tid * DD;
  for (int d = 0; d < DD; ++d) acc += pl[d] * wp[d];
  h1[tid] = gelu_f(acc);
  __syncthreads();
  if (tid < 2){
    float o = b2[tid];
    const float* w2p = w2 + tid * 128;
    for (int c = 0; c < 128; ++c) o += h1[c] * w2p[c];
    out[b * 2 + tid] = o;
  }
}

// =========================== launcher ===========================
static void gemm128(hipStream_t s, const h16* A, const h16* W, int M, int N, int K,
                    int lda, int ldw, int ldc, int Z,
                    long long sAh, long long sAl, long long sWh, long long sWl,
                    long long sCh, long long sCl,
                    const float* bias, const float* sc, const float* off,
                    const h16* addh, float* outf, h16* outh){
  dim3 g(N/128, M/128, Z);
  k_gemm_h<128><<<g, 256, 0, s>>>(A, W, sAh, sAl, sWh, sWl, sCh, sCl,
                                  lda, ldw, ldc, K, bias, sc, off, addh, outf, outh);
}
static void gemm64(hipStream_t s, const h16* A, const h16* W, int M, int N, int K,
                   int lda, int ldw, int ldc, int Z,
                   long long sAh, long long sAl, long long sWh, long long sWl,
                   long long sCh, long long sCl,
                   const float* bias, const h16* addh, float* outf, h16* outh){
  dim3 g(N/64, M/128, Z);
  k_gemm_h<64><<<g, 256, 0, s>>>(A, W, sAh, sAl, sWh, sWl, sCh, sCl,
                                 lda, ldw, ldc, K, bias, nullptr, nullptr, addh, outf, outh);
}

extern "C" void kernel_launch(void* const* d_in, const int* in_sizes, int n_in,
                              void* d_out, int out_size, void* d_ws, size_t ws_size,
                              hipStream_t stream){
  (void)in_sizes; (void)n_in; (void)out_size;
  const float* w2v      = (const float*)d_in[0];
  const float* cqcc     = (const float*)d_in[1];
  const float* conv1_w  = (const float*)d_in[2];
  const float* conv1_b  = (const float*)d_in[3];
  const float* bn1_g    = (const float*)d_in[4];
  const float* bn1_b    = (const float*)d_in[5];
  const float* bn1_m    = (const float*)d_in[6];
  const float* bn1_v    = (const float*)d_in[7];
  const float* conv2_w  = (const float*)d_in[8];
  const float* conv2_b  = (const float*)d_in[9];
  const float* bn2_g    = (const float*)d_in[10];
  const float* bn2_b    = (const float*)d_in[11];
  const float* bn2_m    = (const float*)d_in[12];
  const float* bn2_v    = (const float*)d_in[13];
  const float* pos_embed= (const float*)d_in[14];
  const float* lnq_g    = (const float*)d_in[15];
  const float* lnq_b    = (const float*)d_in[16];
  const float* lnkv_g   = (const float*)d_in[17];
  const float* lnkv_b   = (const float*)d_in[18];
  const float* a1_in_w  = (const float*)d_in[19];
  const float* a1_in_b  = (const float*)d_in[20];
  const float* a1_out_w = (const float*)d_in[21];
  const float* a1_out_b = (const float*)d_in[22];
  const float* a2_in_w  = (const float*)d_in[23];
  const float* a2_in_b  = (const float*)d_in[24];
  const float* a2_out_w = (const float*)d_in[25];
  const float* a2_out_b = (const float*)d_in[26];
  const float* gat_fc_w = (const float*)d_in[27];
  const float* gat_fc_b = (const float*)d_in[28];
  const float* gat_a_w  = (const float*)d_in[29];
  // d_in[30] gat_a_b: cancels in softmax over j — unused.
  const float* gln_g    = (const float*)d_in[31];
  const float* gln_b    = (const float*)d_in[32];
  const float* clf_w1   = (const float*)d_in[33];
  const float* clf_b1   = (const float*)d_in[34];
  const float* clf_w2   = (const float*)d_in[35];
  const float* clf_b2   = (const float*)d_in[36];

  char* wsp = (char*)d_ws;
  auto F = [&](size_t bytes){ char* p = wsp; wsp += (bytes + 255) & ~(size_t)255; return p; };
  float* Abuf = (float*)F(25165824);        // cq  -> later xb (f32)
  float* Bbuf = (float*)F(25165824);        // wpl -> later xh (f16 half)
  h16* L1   = (h16*)F(12582912);            // LN out / Ob / reused
  h16* L2   = (h16*)F(12582912);            // LN out / o1h
  h16* Qh   = (h16*)F(12582912);            // Q / gat h
  h16* Kh   = (h16*)F(12582912);            // K  (also x1 f32)
  h16* Vh   = (h16*)F(12582912);            // V  (also im2col A2)
  h16* VT   = (h16*)F(12582912);            // V^T (also L4 LN buf)
  h16* Sb   = (h16*)F(67108864);            // scores (also x2f f32)
  h16* w_a1in  = (h16*)F(3538944);
  h16* w_a1out = (h16*)F(1179648);
  h16* w_a2in  = (h16*)F(3538944);
  h16* w_a2out = (h16*)F(1179648);
  h16* w_gat   = (h16*)F(3538944);
  h16* w_c2    = (h16*)F(589824);
  float* scb   = (float*)F(3072);
  float* offb  = (float*)F(3072);
  float* sj    = (float*)F(32768);
  float* alpha = (float*)F(32768);
  float* ctxb  = (float*)F(24576);
  float* pooled= (float*)F(24576);
  if ((size_t)(wsp - (char*)d_ws) > ws_size) return;

  float* x1  = (float*)Kh;     // 8.19 MB f32 (conv1 out)
  h16*   A2  = Vh;             // im2col buffer
  float* x2f = (float*)Sb;     // 49.2 MB f32 (conv2 out, [b][t][768])
  h16*   o1h = L2;             // MHA1 output (f16)
  h16*   L4  = VT;             // LNkv(cq) for MHA2
  h16*   Ob  = L1;             // attention output (f16)
  float* xb  = Abuf;           // GAT running state f32
  h16*   xh  = (h16*)Bbuf;     // f16 copy of xb
  h16*   hh  = Qh;             // GAT h

  const size_t S = (size_t)BBATCH * NSEQ * DD;
  const int EW = (int)((S + 255) / 256);
  const long long PH = (long long)NSEQ * DD;       // 786432 (per-batch elems)
  const long long SS = (long long)NSEQ * NSEQ;     // 1048576

  // --- weight casts + bn prep ---
  k_cast<<<(1769472+255)/256, 256, 0, stream>>>(a1_in_w,  w_a1in,  1769472);
  k_cast<<<(589824+255)/256,  256, 0, stream>>>(a1_out_w, w_a1out, 589824);
  k_cast<<<(1769472+255)/256, 256, 0, stream>>>(a2_in_w,  w_a2in,  1769472);
  k_cast<<<(589824+255)/256,  256, 0, stream>>>(a2_out_w, w_a2out, 589824);
  k_cast<<<(1769472+255)/256, 256, 0, stream>>>(gat_fc_w, w_gat,   1769472);
  k_cast<<<(294912+255)/256,  256, 0, stream>>>(conv2_w,  w_c2,    294912);
  k_bnprep<<<3, 256, 0, stream>>>(conv2_b, bn2_g, bn2_b, bn2_m, bn2_v, scb, offb);

  // --- front-end convs ---
  k_conv1t<<<dim3(8, 4, BBATCH), 256, 0, stream>>>(cqcc, conv1_w, conv1_b,
      bn1_g, bn1_b, bn1_m, bn1_v, x1);
  k_im2col<<<(16000*384+255)/256, 256, 0, stream>>>(x1, A2);
  gemm128(stream, A2, w_c2, 16000, DD, 384, 384, 384, DD, 1,
          0,0,0,0,0,0, nullptr, scb, offb, nullptr, x2f, nullptr);
  k_interp2<<<EW, 256, 0, stream>>>(x2f, pos_embed, Abuf);
  k_addpos<<<EW, 256, 0, stream>>>(w2v, pos_embed, Bbuf);

  const int NR = BBATCH * NSEQ;  // 8192 rows

  // ================= MHA1: q = LNq(cq), kv = LNkv(w) =================
  k_ln2<<<NR, 256, 0, stream>>>(Abuf, nullptr, lnq_g,  lnq_b,  nullptr, L1);
  k_ln2<<<NR, 256, 0, stream>>>(Bbuf, nullptr, lnkv_g, lnkv_b, nullptr, L2);
  gemm128(stream, L1, w_a1in,            NR, DD, DD, DD, DD, DD, 1, 0,0,0,0,0,0,
          a1_in_b,        nullptr, nullptr, nullptr, nullptr, Qh);
  gemm128(stream, L2, w_a1in + 589824,   NR, DD, DD, DD, DD, DD, 1, 0,0,0,0,0,0,
          a1_in_b + DD,   nullptr, nullptr, nullptr, nullptr, Kh);
  gemm128(stream, L2, w_a1in + 2*589824, NR, DD, DD, DD, DD, DD, 1, 0,0,0,0,0,0,
          a1_in_b + 2*DD, nullptr, nullptr, nullptr, nullptr, Vh);
  k_trV<<<dim3(32, 6, 32), 256, 0, stream>>>(Vh, VT);
  gemm128(stream, Qh, Kh, NSEQ, NSEQ, HDIM, DD, DD, NSEQ, 32,
          PH, HDIM, PH, HDIM, 4*SS, SS,
          nullptr, nullptr, nullptr, nullptr, nullptr, Sb);
  k_softmax_s<<<32*NSEQ, 256, 0, stream>>>(Sb);
  gemm64(stream, Sb, VT, NSEQ, HDIM, NSEQ, NSEQ, NSEQ, DD, 32,
         4*SS, SS, 4*(long long)HDIM*NSEQ, (long long)HDIM*NSEQ, PH, HDIM,
         nullptr, nullptr, nullptr, Ob);
  gemm128(stream, Ob, w_a1out, NR, DD, DD, DD, DD, DD, 1, 0,0,0,0,0,0,
          a1_out_b, nullptr, nullptr, nullptr, nullptr, o1h);

  // ================= MHA2: q = LNq(w), kv = LNkv(cq) =================
  k_ln2<<<NR, 256, 0, stream>>>(Bbuf, nullptr, lnq_g,  lnq_b,  nullptr, L1);
  k_ln2<<<NR, 256, 0, stream>>>(Abuf, nullptr, lnkv_g, lnkv_b, nullptr, L4);
  gemm128(stream, L1, w_a2in,            NR, DD, DD, DD, DD, DD, 1, 0,0,0,0,0,0,
          a2_in_b,        nullptr, nullptr, nullptr, nullptr, Qh);
  gemm128(stream, L4, w_a2in + 589824,   NR, DD, DD, DD, DD, DD, 1, 0,0,0,0,0,0,
          a2_in_b + DD,   nullptr, nullptr, nullptr, nullptr, Kh);
  gemm128(stream, L4, w_a2in + 2*589824, NR, DD, DD, DD, DD, DD, 1, 0,0,0,0,0,0,
          a2_in_b + 2*DD, nullptr, nullptr, nullptr, nullptr, Vh);
  k_trV<<<dim3(32, 6, 32), 256, 0, stream>>>(Vh, VT);
  gemm128(stream, Qh, Kh, NSEQ, NSEQ, HDIM, DD, DD, NSEQ, 32,
          PH, HDIM, PH, HDIM, 4*SS, SS,
          nullptr, nullptr, nullptr, nullptr, nullptr, Sb);
  k_softmax_s<<<32*NSEQ, 256, 0, stream>>>(Sb);
  gemm64(stream, Sb, VT, NSEQ, HDIM, NSEQ, NSEQ, NSEQ, DD, 32,
         4*SS, SS, 4*(long long)HDIM*NSEQ, (long long)HDIM*NSEQ, PH, HDIM,
         nullptr, nullptr, nullptr, Ob);
  // out-proj2 + add out1 -> xb (f32) and xh (f16)
  gemm128(stream, Ob, w_a2out, NR, DD, DD, DD, DD, DD, 1, 0,0,0,0,0,0,
          a2_out_b, nullptr, nullptr, o1h, xb, xh);

  // ================= GAT x3 (softmax over j collapses) =================
  for (int l = 0; l < 3; ++l){
    gemm128(stream, xh, w_gat + (size_t)l*589824, NR, DD, DD, DD, DD, DD, 1,
            0,0,0,0,0,0, gat_fc_b + l*DD, nullptr, nullptr, nullptr, nullptr, hh);
    k_rowdot<<<NR, 256, 0, stream>>>(hh, gat_a_w + l*2*DD + DD, sj);
    k_softmax1024<<<BBATCH, 256, 0, stream>>>(sj, alpha);
    k_ctx<<<dim3(3, BBATCH), 256, 0, stream>>>(alpha, hh, ctxb);
    k_ln2<<<NR, 256, 0, stream>>>(xb, ctxb, gln_g + l*DD, gln_b + l*DD, xb, xh);
  }

  k_pool<<<dim3(3, BBATCH), 256, 0, stream>>>(xb, pooled);
  k_clf<<<BBATCH, 128, 0, stream>>>(pooled, clf_w1, clf_b1, clf_w2, clf_b2,
                                    (float*)d_out);
}

// Round 3
// 975.727 us; speedup vs baseline: 6.4260x; 1.2712x over previous
//
#include <hip/hip_runtime.h>
#include <math.h>

#define DD 768
#define NH 4
#define HDIM 192
#define BBATCH 8
#define NSEQ 1024
#define TLEN 2000

typedef _Float16 h16;
typedef _Float16 half8v __attribute__((ext_vector_type(8)));
typedef _Float16 half4v __attribute__((ext_vector_type(4)));
typedef float f32x4 __attribute__((ext_vector_type(4)));

__device__ __forceinline__ float gelu_f(float x){
  return 0.5f * x * (1.0f + erff(x * 0.70710678118654752440f));
}
__device__ __forceinline__ float wave_sum(float v){
  #pragma unroll
  for (int off = 32; off; off >>= 1) v += __shfl_xor(v, off);
  return v;
}
__device__ __forceinline__ float wave_max(float v){
  #pragma unroll
  for (int off = 32; off; off >>= 1) v = fmaxf(v, __shfl_xor(v, off));
  return v;
}
__device__ __forceinline__ void gload16(const h16* g, h16* l){
  __builtin_amdgcn_global_load_lds(
      (const __attribute__((address_space(1))) void*)g,
      (__attribute__((address_space(3))) void*)l, 16, 0, 0);
}

// ---------------- f32 -> f16 cast ----------------
__global__ __launch_bounds__(256) void k_cast(const float* __restrict__ s,
    h16* __restrict__ d, int n){
  int i = blockIdx.x * 256 + threadIdx.x;
  if (i < n) d[i] = (h16)s[i];
}

// ---------------- conv1 (20->128, k=3) + bn + gelu, LDS tiled ----------------
__global__ __launch_bounds__(256) void k_conv1t(const float* __restrict__ cqcc,
    const float* __restrict__ w, const float* __restrict__ bias,
    const float* __restrict__ g, const float* __restrict__ be,
    const float* __restrict__ mm, const float* __restrict__ vv,
    float* __restrict__ out){
  __shared__ float xs[20][258];
  __shared__ float wsm[32*60];
  const int t0 = blockIdx.x * 256;
  const int ocg = blockIdx.y, b = blockIdx.z;
  const int tid = threadIdx.x;
  for (int idx = tid; idx < 20*258; idx += 256){
    int ic = idx / 258, tt = idx % 258;
    int t = t0 + tt - 1;
    xs[ic][tt] = (t >= 0 && t < TLEN) ? cqcc[((size_t)b*20 + ic)*TLEN + t] : 0.f;
  }
  for (int idx = tid; idx < 32*60; idx += 256)
    wsm[idx] = w[ocg*32*60 + idx];
  __syncthreads();
  int t = t0 + tid;
  if (t >= TLEN) return;
  float acc[32] = {};
  for (int ic = 0; ic < 20; ++ic){
    float x0 = xs[ic][tid], x1v = xs[ic][tid+1], x2v = xs[ic][tid+2];
    #pragma unroll
    for (int oc = 0; oc < 32; ++oc){
      const float* wp = &wsm[(oc*20 + ic)*3];
      acc[oc] += wp[0]*x0 + wp[1]*x1v + wp[2]*x2v;
    }
  }
  #pragma unroll 4
  for (int oc = 0; oc < 32; ++oc){
    int c = ocg*32 + oc;
    float s = rsqrtf(vv[c] + 1e-5f) * g[c];
    float val = (acc[oc] + bias[c] - mm[c]) * s + be[c];
    out[((size_t)b*128 + c)*TLEN + t] = gelu_f(val);
  }
}

// ---------------- im2col for conv2: x1[b][128][2000] -> A2[16000][384] f16 ---
__global__ __launch_bounds__(256) void k_im2col(const float* __restrict__ x1,
    h16* __restrict__ A2){
  int idx = blockIdx.x * 256 + threadIdx.x;
  if (idx >= 16000*384) return;
  int c = idx % 384, m = idx / 384;
  int b = m / TLEN, t = m % TLEN;
  int ic = c / 3, kh = c % 3;
  int ts = t + kh - 1;
  float v = (ts < 0 || ts >= TLEN) ? 0.f : x1[((size_t)b*128 + ic)*TLEN + ts];
  A2[idx] = (h16)v;
}

// ---------------- BN epilogue constants for conv2 ----------------
__global__ void k_bnprep(const float* __restrict__ cb, const float* __restrict__ g,
    const float* __restrict__ be, const float* __restrict__ m,
    const float* __restrict__ v, float* __restrict__ sc, float* __restrict__ off){
  int i = blockIdx.x * 256 + threadIdx.x;
  if (i >= DD) return;
  float s = g[i] * rsqrtf(v[i] + 1e-5f);
  sc[i] = s;
  off[i] = (cb[i] - m[i]) * s + be[i];
}

// ---------------- interp (2000->1024) on [b][t][768] layout + pos ----------
__global__ __launch_bounds__(256) void k_interp2(const float* __restrict__ x2,
    const float* __restrict__ pe, float* __restrict__ cq){
  int idx = blockIdx.x * 256 + threadIdx.x;
  if (idx >= BBATCH * NSEQ * DD) return;
  int d = idx % DD; int i = (idx / DD) % NSEQ; int b = idx / (DD * NSEQ);
  float p = (i + 0.5f) * ((float)TLEN / (float)NSEQ) - 0.5f;
  p = fminf(fmaxf(p, 0.f), (float)(TLEN - 1));
  int lo = (int)floorf(p);
  int hi = min(lo + 1, TLEN - 1);
  float w = p - (float)lo;
  const float* base = x2 + (size_t)b * TLEN * DD + d;
  float val = base[(size_t)lo * DD] * (1.f - w) + base[(size_t)hi * DD] * w;
  cq[idx] = val + pe[(size_t)i * DD + d];
}

__global__ __launch_bounds__(256) void k_addpos(const float* __restrict__ x,
    const float* __restrict__ pe, float* __restrict__ y){
  int idx = blockIdx.x * 256 + threadIdx.x;
  if (idx >= BBATCH * NSEQ * DD) return;
  int d = idx % DD; int i = (idx / DD) % NSEQ;
  y[idx] = x[idx] + pe[(size_t)i * DD + d];
}

// ---------------- layernorm 768, optional ctx add, dual outputs ----------
__global__ __launch_bounds__(256) void k_ln2(const float* __restrict__ in,
    const float* __restrict__ ctx, const float* __restrict__ g,
    const float* __restrict__ be, float* __restrict__ outf, h16* __restrict__ outh){
  __shared__ float ss[4], sqq[4];
  int row = blockIdx.x, tid = threadIdx.x;
  const float* ip = in + (size_t)row * DD;
  int b = row >> 10;
  float v[3]; float s = 0.f, sq = 0.f;
  #pragma unroll
  for (int j = 0; j < 3; ++j){
    int d = j * 256 + tid;
    float x = ip[d];
    if (ctx) x += ctx[b * DD + d];
    v[j] = x; s += x; sq += x * x;
  }
  s = wave_sum(s); sq = wave_sum(sq);
  int w = tid >> 6;
  if ((tid & 63) == 0){ ss[w] = s; sqq[w] = sq; }
  __syncthreads();
  s  = ss[0] + ss[1] + ss[2] + ss[3];
  sq = sqq[0] + sqq[1] + sqq[2] + sqq[3];
  float mean = s * (1.f / DD);
  float var  = sq * (1.f / DD) - mean * mean;
  float r = rsqrtf(var + 1e-5f);
  #pragma unroll
  for (int j = 0; j < 3; ++j){
    int d = j * 256 + tid;
    float y = (v[j] - mean) * r * g[d] + be[d];
    if (outf) outf[(size_t)row * DD + d] = y;
    if (outh) outh[(size_t)row * DD + d] = (h16)y;
  }
}

// ---------------- f16 MFMA GEMM: C[M,N] = A[M,K] @ W[N,K]^T ------------------
// BM=128, BK=64, 4 waves (2x2). global_load_lds(16B) staging into LINEAR LDS
// with inverse-XOR-swizzled global source; ds_read applies the same XOR
// (chunk ^= row&7 on 16B chunks) -> uniform 8-lane/slot b128 reads (optimal).
// Batched via z-decode: base = (z>>2)*s_hi + (z&3)*s_lo.
template<int BN>
__global__ __launch_bounds__(256) void k_gemm_h(
    const h16* __restrict__ A, const h16* __restrict__ W,
    long long sA_hi, long long sA_lo, long long sW_hi, long long sW_lo,
    long long sC_hi, long long sC_lo,
    int lda, int ldw, int ldc, int K,
    const float* __restrict__ bias, const float* __restrict__ sc,
    const float* __restrict__ off,
    const h16* __restrict__ addh, float* __restrict__ outf, h16* __restrict__ outh)
{
  __shared__ h16 Als[128*64];
  __shared__ h16 Bls[BN*64];
  const int tid = threadIdx.x;
  const int z = blockIdx.z, zh = z >> 2, zl = z & 3;
  const size_t aBase = (size_t)(zh * sA_hi + zl * sA_lo);
  const size_t wBase = (size_t)(zh * sW_hi + zl * sW_lo);
  const size_t cBase = (size_t)(zh * sC_hi + zl * sC_lo);
  const int n0 = blockIdx.x * BN, m0 = blockIdx.y * 128;
  const int lane = tid & 63, wid = tid >> 6;
  const int wr = wid >> 1, wc = wid & 1;
  const int lr = lane & 15, lg = lane >> 4;
  constexpr int NR = BN / 32;
  f32x4 acc[4][NR] = {};
  const h16* Ab = A + aBase;
  const h16* Wb = W + wBase;
  for (int kt = 0; kt < K; kt += 64){
    __syncthreads();                    // prev ds_reads done before overwrite
    #pragma unroll
    for (int i = 0; i < 4; ++i){
      int p = i*256 + tid;
      int row = p >> 3, chp = p & 7;
      int ch = chp ^ (row & 7);
      gload16(Ab + (size_t)(m0+row)*lda + kt + ch*8, &Als[p*8]);
    }
    #pragma unroll
    for (int i = 0; i < BN/32; ++i){
      int p = i*256 + tid;
      int row = p >> 3, chp = p & 7;
      int ch = chp ^ (row & 7);
      gload16(Wb + (size_t)(n0+row)*ldw + kt + ch*8, &Bls[p*8]);
    }
    __syncthreads();                    // compiler drains vmcnt(0) before barrier
    #pragma unroll
    for (int kk = 0; kk < 2; ++kk){
      half8v af[4], bf[NR];
      #pragma unroll
      for (int mi = 0; mi < 4; ++mi){
        int row = wr*64 + mi*16 + lr;
        int chp = (kk*4 + lg) ^ (row & 7);
        af[mi] = *(const half8v*)&Als[row*64 + chp*8];
      }
      #pragma unroll
      for (int ni = 0; ni < NR; ++ni){
        int row = wc*(BN/2) + ni*16 + lr;
        int chp = (kk*4 + lg) ^ (row & 7);
        bf[ni] = *(const half8v*)&Bls[row*64 + chp*8];
      }
      #pragma unroll
      for (int mi = 0; mi < 4; ++mi)
        #pragma unroll
        for (int ni = 0; ni < NR; ++ni)
          acc[mi][ni] = __builtin_amdgcn_mfma_f32_16x16x32_f16(af[mi], bf[ni], acc[mi][ni], 0, 0, 0);
    }
  }
  #pragma unroll
  for (int mi = 0; mi < 4; ++mi){
    #pragma unroll
    for (int ni = 0; ni < NR; ++ni){
      int col = n0 + wc*(BN/2) + ni*16 + lr;
      int rowb = m0 + wr*64 + mi*16 + lg*4;
      float cb = bias ? bias[col] : 0.f;
      #pragma unroll
      for (int r = 0; r < 4; ++r){
        int row = rowb + r;
        size_t idx = cBase + (size_t)row * ldc + col;
        float v = acc[mi][ni][r];
        if (sc){ v = v * sc[col] + off[col]; v = gelu_f(v); }
        else v += cb;
        if (addh) v += (float)addh[idx];
        if (outf) outf[idx] = v;
        if (outh) outh[idx] = (h16)v;
      }
    }
  }
}

// ---------------- V transpose: Vh[b][q][h*192+d] -> VT[bh][d][q] -------------
__global__ __launch_bounds__(256) void k_trV(const h16* __restrict__ Vh,
    h16* __restrict__ VT){
  __shared__ h16 tile[32][36];
  const int z = blockIdx.z, b = z >> 2, h = z & 3;
  const int q0 = blockIdx.x * 32, d0 = blockIdx.y * 32;
  const int t = threadIdx.x;
  {
    int qq = t >> 3, dg = (t & 7) * 4;
    const h16* src = Vh + (size_t)b*NSEQ*DD + h*HDIM + (size_t)(q0+qq)*DD + d0 + dg;
    half4v v = *(const half4v*)src;
    *(half4v*)&tile[qq][dg] = v;
  }
  __syncthreads();
  {
    int dd = t >> 3, qg = (t & 7) * 4;
    half4v ov;
    ov[0] = tile[qg+0][dd]; ov[1] = tile[qg+1][dd];
    ov[2] = tile[qg+2][dd]; ov[3] = tile[qg+3][dd];
    *(half4v*)(VT + (size_t)z*HDIM*NSEQ + (size_t)(d0+dd)*NSEQ + q0 + qg) = ov;
  }
}

// ------------- softmax over S rows, vectorized: 2 rows/block -----------------
__global__ __launch_bounds__(256) void k_softmax_s(h16* __restrict__ S){
  __shared__ float redm[4], reds[4];
  const float SCALE = 0.07216878364870322f;  // 1/sqrt(192)
  const int tid = threadIdx.x;
  const int r = tid >> 7, t = tid & 127;
  h16* p = S + (size_t)(blockIdx.x*2 + r) * 1024 + t*8;
  half8v v = *(const half8v*)p;
  float f[8]; float mx = -1e30f;
  #pragma unroll
  for (int j = 0; j < 8; ++j){ f[j] = (float)v[j] * SCALE; mx = fmaxf(mx, f[j]); }
  mx = wave_max(mx);
  int w = tid >> 6;
  if ((tid & 63) == 0) redm[w] = mx;
  __syncthreads();
  mx = fmaxf(redm[r*2], redm[r*2+1]);
  float s = 0.f;
  #pragma unroll
  for (int j = 0; j < 8; ++j){ f[j] = __expf(f[j] - mx); s += f[j]; }
  s = wave_sum(s);
  if ((tid & 63) == 0) reds[w] = s;
  __syncthreads();
  float inv = 1.0f / (reds[r*2] + reds[r*2+1]);
  half8v o;
  #pragma unroll
  for (int j = 0; j < 8; ++j) o[j] = (h16)(f[j] * inv);
  *(half8v*)p = o;
}

// ---------------- GAT helpers ----------------
__global__ __launch_bounds__(128) void k_rowdot(const h16* __restrict__ h,
    const float* __restrict__ aw, float* __restrict__ sj){
  __shared__ float red[2];
  int row = blockIdx.x, tid = threadIdx.x;
  float s = 0.f;
  if (tid < 96){
    half8v v = *(const half8v*)(h + (size_t)row * DD + tid*8);
    #pragma unroll
    for (int j = 0; j < 8; ++j) s += (float)v[j] * aw[tid*8 + j];
  }
  s = wave_sum(s);
  if ((tid & 63) == 0) red[tid >> 6] = s;
  __syncthreads();
  if (tid == 0) sj[row] = red[0] + red[1];
}

__global__ __launch_bounds__(256) void k_softmax1024(const float* __restrict__ x,
    float* __restrict__ y){
  __shared__ float red[4];
  int b = blockIdx.x, tid = threadIdx.x;
  const float* ip = x + b * NSEQ;
  float v[4]; float mx = -1e30f;
  #pragma unroll
  for (int j = 0; j < 4; ++j){ v[j] = ip[j * 256 + tid]; mx = fmaxf(mx, v[j]); }
  mx = wave_max(mx);
  if ((tid & 63) == 0) red[tid >> 6] = mx;
  __syncthreads();
  mx = fmaxf(fmaxf(red[0], red[1]), fmaxf(red[2], red[3]));
  __syncthreads();
  float s = 0.f;
  #pragma unroll
  for (int j = 0; j < 4; ++j){ v[j] = __expf(v[j] - mx); s += v[j]; }
  s = wave_sum(s);
  if ((tid & 63) == 0) red[tid >> 6] = s;
  __syncthreads();
  s = red[0] + red[1] + red[2] + red[3];
  float inv = 1.0f / s;
  #pragma unroll
  for (int j = 0; j < 4; ++j) y[b * NSEQ + j * 256 + tid] = v[j] * inv;
}

// ctx two-stage: stage1 partial over 64-j chunks, stage2 combine
__global__ __launch_bounds__(256) void k_ctx1(const float* __restrict__ alpha,
    const h16* __restrict__ h, float* __restrict__ part){
  int d = blockIdx.x * 256 + threadIdx.x;
  int b = blockIdx.y, pc = blockIdx.z;
  if (d >= DD) return;
  float acc = 0.f;
  const h16* hp = h + ((size_t)b * NSEQ + pc * 64) * DD + d;
  const float* ap = alpha + b * NSEQ + pc * 64;
  #pragma unroll 4
  for (int j = 0; j < 64; ++j) acc += ap[j] * (float)hp[(size_t)j * DD];
  part[(size_t)(b * 16 + pc) * DD + d] = acc;
}
__global__ __launch_bounds__(256) void k_ctx2(const float* __restrict__ part,
    float* __restrict__ ctx){
  int d = blockIdx.x * 256 + threadIdx.x;
  int b = blockIdx.y;
  if (d >= DD) return;
  float acc = 0.f;
  #pragma unroll
  for (int p = 0; p < 16; ++p) acc += part[(size_t)(b * 16 + p) * DD + d];
  ctx[b * DD + d] = acc;
}

// ---------------- pooling + classifier ----------------
__global__ __launch_bounds__(256) void k_pool(const float* __restrict__ x,
    float* __restrict__ pooled){
  int d = blockIdx.x * 256 + threadIdx.x;
  int b = blockIdx.y;
  if (d >= DD) return;
  float acc = 0.f;
  const float* xp = x + (size_t)b * NSEQ * DD + d;
  for (int i = 0; i < NSEQ; ++i) acc += xp[(size_t)i * DD];
  pooled[b * DD + d] = acc * (1.0f / NSEQ);
}

__global__ __launch_bounds__(128) void k_clf(const float* __restrict__ pooled,
    const float* __restrict__ w1, const float* __restrict__ b1,
    const float* __restrict__ w2, const float* __restrict__ b2,
    float* __restrict__ out){
  __shared__ float pl[DD];
  __shared__ float h1[128];
  int b = blockIdx.x, tid = threadIdx.x;
  #pragma unroll
  for (int j = 0; j < 6; ++j) pl[j * 128 + tid] = pooled[b * DD + j * 128 + tid];
  __syncthreads();
  float acc = b1[tid];
  const float* wp = w1 + (size_t)tid * DD;
  for (int d = 0; d < DD; ++d) acc += pl[d] * wp[d];
  h1[tid] = gelu_f(acc);
  __syncthreads();
  if (tid < 2){
    float o = b2[tid];
    const float* w2p = w2 + tid * 128;
    for (int c = 0; c < 128; ++c) o += h1[c] * w2p[c];
    out[b * 2 + tid] = o;
  }
}

// =========================== launcher ===========================
static void gemm128(hipStream_t s, const h16* A, const h16* W, int M, int N, int K,
                    int lda, int ldw, int ldc, int Z,
                    long long sAh, long long sAl, long long sWh, long long sWl,
                    long long sCh, long long sCl,
                    const float* bias, const float* sc, const float* off,
                    const h16* addh, float* outf, h16* outh){
  dim3 g(N/128, M/128, Z);
  k_gemm_h<128><<<g, 256, 0, s>>>(A, W, sAh, sAl, sWh, sWl, sCh, sCl,
                                  lda, ldw, ldc, K, bias, sc, off, addh, outf, outh);
}
static void gemm64(hipStream_t s, const h16* A, const h16* W, int M, int N, int K,
                   int lda, int ldw, int ldc, int Z,
                   long long sAh, long long sAl, long long sWh, long long sWl,
                   long long sCh, long long sCl,
                   const float* bias, const h16* addh, float* outf, h16* outh){
  dim3 g(N/64, M/128, Z);
  k_gemm_h<64><<<g, 256, 0, s>>>(A, W, sAh, sAl, sWh, sWl, sCh, sCl,
                                 lda, ldw, ldc, K, bias, nullptr, nullptr, addh, outf, outh);
}

extern "C" void kernel_launch(void* const* d_in, const int* in_sizes, int n_in,
                              void* d_out, int out_size, void* d_ws, size_t ws_size,
                              hipStream_t stream){
  (void)in_sizes; (void)n_in; (void)out_size;
  const float* w2v      = (const float*)d_in[0];
  const float* cqcc     = (const float*)d_in[1];
  const float* conv1_w  = (const float*)d_in[2];
  const float* conv1_b  = (const float*)d_in[3];
  const float* bn1_g    = (const float*)d_in[4];
  const float* bn1_b    = (const float*)d_in[5];
  const float* bn1_m    = (const float*)d_in[6];
  const float* bn1_v    = (const float*)d_in[7];
  const float* conv2_w  = (const float*)d_in[8];
  const float* conv2_b  = (const float*)d_in[9];
  const float* bn2_g    = (const float*)d_in[10];
  const float* bn2_b    = (const float*)d_in[11];
  const float* bn2_m    = (const float*)d_in[12];
  const float* bn2_v    = (const float*)d_in[13];
  const float* pos_embed= (const float*)d_in[14];
  const float* lnq_g    = (const float*)d_in[15];
  const float* lnq_b    = (const float*)d_in[16];
  const float* lnkv_g   = (const float*)d_in[17];
  const float* lnkv_b   = (const float*)d_in[18];
  const float* a1_in_w  = (const float*)d_in[19];
  const float* a1_in_b  = (const float*)d_in[20];
  const float* a1_out_w = (const float*)d_in[21];
  const float* a1_out_b = (const float*)d_in[22];
  const float* a2_in_w  = (const float*)d_in[23];
  const float* a2_in_b  = (const float*)d_in[24];
  const float* a2_out_w = (const float*)d_in[25];
  const float* a2_out_b = (const float*)d_in[26];
  const float* gat_fc_w = (const float*)d_in[27];
  const float* gat_fc_b = (const float*)d_in[28];
  const float* gat_a_w  = (const float*)d_in[29];
  // d_in[30] gat_a_b: cancels in softmax over j — unused.
  const float* gln_g    = (const float*)d_in[31];
  const float* gln_b    = (const float*)d_in[32];
  const float* clf_w1   = (const float*)d_in[33];
  const float* clf_b1   = (const float*)d_in[34];
  const float* clf_w2   = (const float*)d_in[35];
  const float* clf_b2   = (const float*)d_in[36];

  char* wsp = (char*)d_ws;
  auto F = [&](size_t bytes){ char* p = wsp; wsp += (bytes + 255) & ~(size_t)255; return p; };
  float* Abuf = (float*)F(25165824);        // cq  -> later xb (f32)
  float* Bbuf = (float*)F(25165824);        // wpl -> later xh (f16 half)
  h16* L1   = (h16*)F(12582912);            // LN out / Ob
  h16* L2   = (h16*)F(12582912);            // LN out / o1h
  h16* Qh   = (h16*)F(12582912);            // Q / gat h
  h16* Kh   = (h16*)F(12582912);            // K  (also x1 f32)
  h16* Vh   = (h16*)F(12582912);            // V  (also im2col A2)
  h16* VT   = (h16*)F(12582912);            // V^T (also L4 LN buf)
  h16* Sb   = (h16*)F(67108864);            // scores (also x2f f32)
  h16* w_a1in  = (h16*)F(3538944);
  h16* w_a1out = (h16*)F(1179648);
  h16* w_a2in  = (h16*)F(3538944);
  h16* w_a2out = (h16*)F(1179648);
  h16* w_gat   = (h16*)F(3538944);
  h16* w_c2    = (h16*)F(589824);
  float* scb   = (float*)F(3072);
  float* offb  = (float*)F(3072);
  float* sj    = (float*)F(32768);
  float* alpha = (float*)F(32768);
  float* ctxb  = (float*)F(24576);
  float* pooled= (float*)F(24576);
  float* partb = (float*)F(393216);         // ctx partials 8*16*768 f32
  if ((size_t)(wsp - (char*)d_ws) > ws_size) return;

  float* x1  = (float*)Kh;     // conv1 out (f32)
  h16*   A2  = Vh;             // im2col buffer
  float* x2f = (float*)Sb;     // conv2 out f32 [b][t][768]
  h16*   o1h = L2;             // MHA1 output (f16)
  h16*   L4  = VT;             // LNkv(cq) for MHA2
  h16*   Ob  = L1;             // attention output (f16)
  float* xb  = Abuf;           // GAT running state f32
  h16*   xh  = (h16*)Bbuf;     // f16 copy of xb
  h16*   hh  = Qh;             // GAT h

  const size_t S = (size_t)BBATCH * NSEQ * DD;
  const int EW = (int)((S + 255) / 256);
  const long long PH = (long long)NSEQ * DD;       // per-batch elems
  const long long SS = (long long)NSEQ * NSEQ;

  // --- weight casts + bn prep ---
  k_cast<<<(1769472+255)/256, 256, 0, stream>>>(a1_in_w,  w_a1in,  1769472);
  k_cast<<<(589824+255)/256,  256, 0, stream>>>(a1_out_w, w_a1out, 589824);
  k_cast<<<(1769472+255)/256, 256, 0, stream>>>(a2_in_w,  w_a2in,  1769472);
  k_cast<<<(589824+255)/256,  256, 0, stream>>>(a2_out_w, w_a2out, 589824);
  k_cast<<<(1769472+255)/256, 256, 0, stream>>>(gat_fc_w, w_gat,   1769472);
  k_cast<<<(294912+255)/256,  256, 0, stream>>>(conv2_w,  w_c2,    294912);
  k_bnprep<<<3, 256, 0, stream>>>(conv2_b, bn2_g, bn2_b, bn2_m, bn2_v, scb, offb);

  // --- front-end convs ---
  k_conv1t<<<dim3(8, 4, BBATCH), 256, 0, stream>>>(cqcc, conv1_w, conv1_b,
      bn1_g, bn1_b, bn1_m, bn1_v, x1);
  k_im2col<<<(16000*384+255)/256, 256, 0, stream>>>(x1, A2);
  gemm128(stream, A2, w_c2, 16000, DD, 384, 384, 384, DD, 1,
          0,0,0,0,0,0, nullptr, scb, offb, nullptr, x2f, nullptr);
  k_interp2<<<EW, 256, 0, stream>>>(x2f, pos_embed, Abuf);
  k_addpos<<<EW, 256, 0, stream>>>(w2v, pos_embed, Bbuf);

  const int NR = BBATCH * NSEQ;  // 8192 rows

  // ================= MHA1: q = LNq(cq), kv = LNkv(w) =================
  k_ln2<<<NR, 256, 0, stream>>>(Abuf, nullptr, lnq_g,  lnq_b,  nullptr, L1);
  k_ln2<<<NR, 256, 0, stream>>>(Bbuf, nullptr, lnkv_g, lnkv_b, nullptr, L2);
  gemm128(stream, L1, w_a1in,            NR, DD, DD, DD, DD, DD, 1, 0,0,0,0,0,0,
          a1_in_b,        nullptr, nullptr, nullptr, nullptr, Qh);
  gemm128(stream, L2, w_a1in + 589824,   NR, DD, DD, DD, DD, DD, 1, 0,0,0,0,0,0,
          a1_in_b + DD,   nullptr, nullptr, nullptr, nullptr, Kh);
  gemm128(stream, L2, w_a1in + 2*589824, NR, DD, DD, DD, DD, DD, 1, 0,0,0,0,0,0,
          a1_in_b + 2*DD, nullptr, nullptr, nullptr, nullptr, Vh);
  k_trV<<<dim3(32, 6, 32), 256, 0, stream>>>(Vh, VT);
  gemm128(stream, Qh, Kh, NSEQ, NSEQ, HDIM, DD, DD, NSEQ, 32,
          PH, HDIM, PH, HDIM, 4*SS, SS,
          nullptr, nullptr, nullptr, nullptr, nullptr, Sb);
  k_softmax_s<<<16*NSEQ, 256, 0, stream>>>(Sb);
  gemm64(stream, Sb, VT, NSEQ, HDIM, NSEQ, NSEQ, NSEQ, DD, 32,
         4*SS, SS, 4*(long long)HDIM*NSEQ, (long long)HDIM*NSEQ, PH, HDIM,
         nullptr, nullptr, nullptr, Ob);
  gemm128(stream, Ob, w_a1out, NR, DD, DD, DD, DD, DD, 1, 0,0,0,0,0,0,
          a1_out_b, nullptr, nullptr, nullptr, nullptr, o1h);

  // ================= MHA2: q = LNq(w), kv = LNkv(cq) =================
  k_ln2<<<NR, 256, 0, stream>>>(Bbuf, nullptr, lnq_g,  lnq_b,  nullptr, L1);
  k_ln2<<<NR, 256, 0, stream>>>(Abuf, nullptr, lnkv_g, lnkv_b, nullptr, L4);
  gemm128(stream, L1, w_a2in,            NR, DD, DD, DD, DD, DD, 1, 0,0,0,0,0,0,
          a2_in_b,        nullptr, nullptr, nullptr, nullptr, Qh);
  gemm128(stream, L4, w_a2in + 589824,   NR, DD, DD, DD, DD, DD, 1, 0,0,0,0,0,0,
          a2_in_b + DD,   nullptr, nullptr, nullptr, nullptr, Kh);
  gemm128(stream, L4, w_a2in + 2*589824, NR, DD, DD, DD, DD, DD, 1, 0,0,0,0,0,0,
          a2_in_b + 2*DD, nullptr, nullptr, nullptr, nullptr, Vh);
  k_trV<<<dim3(32, 6, 32), 256, 0, stream>>>(Vh, VT);
  gemm128(stream, Qh, Kh, NSEQ, NSEQ, HDIM, DD, DD, NSEQ, 32,
          PH, HDIM, PH, HDIM, 4*SS, SS,
          nullptr, nullptr, nullptr, nullptr, nullptr, Sb);
  k_softmax_s<<<16*NSEQ, 256, 0, stream>>>(Sb);
  gemm64(stream, Sb, VT, NSEQ, HDIM, NSEQ, NSEQ, NSEQ, DD, 32,
         4*SS, SS, 4*(long long)HDIM*NSEQ, (long long)HDIM*NSEQ, PH, HDIM,
         nullptr, nullptr, nullptr, Ob);
  // out-proj2 + add out1 -> xb (f32) and xh (f16)
  gemm128(stream, Ob, w_a2out, NR, DD, DD, DD, DD, DD, 1, 0,0,0,0,0,0,
          a2_out_b, nullptr, nullptr, o1h, xb, xh);

  // ================= GAT x3 (softmax over j collapses) =================
  for (int l = 0; l < 3; ++l){
    gemm128(stream, xh, w_gat + (size_t)l*589824, NR, DD, DD, DD, DD, DD, 1,
            0,0,0,0,0,0, gat_fc_b + l*DD, nullptr, nullptr, nullptr, nullptr, hh);
    k_rowdot<<<NR, 128, 0, stream>>>(hh, gat_a_w + l*2*DD + DD, sj);
    k_softmax1024<<<BBATCH, 256, 0, stream>>>(sj, alpha);
    k_ctx1<<<dim3(3, BBATCH, 16), 256, 0, stream>>>(alpha, hh, partb);
    k_ctx2<<<dim3(3, BBATCH), 256, 0, stream>>>(partb, ctxb);
    k_ln2<<<NR, 256, 0, stream>>>(xb, ctxb, gln_g + l*DD, gln_b + l*DD, xb, xh);
  }

  k_pool<<<dim3(3, BBATCH), 256, 0, stream>>>(xb, pooled);
  k_clf<<<BBATCH, 128, 0, stream>>>(pooled, clf_w1, clf_b1, clf_w2, clf_b2,
                                    (float*)d_out);
}

// Round 4
// 845.250 us; speedup vs baseline: 7.4180x; 1.1544x over previous
//
#include <hip/hip_runtime.h>
#include <math.h>

#define DD 768
#define NH 4
#define HDIM 192
#define BBATCH 8
#define NSEQ 1024
#define TLEN 2000

typedef _Float16 h16;
typedef _Float16 half8v __attribute__((ext_vector_type(8)));
typedef _Float16 half4v __attribute__((ext_vector_type(4)));
typedef float f32x4 __attribute__((ext_vector_type(4)));

__device__ __forceinline__ float gelu_f(float x){
  return 0.5f * x * (1.0f + erff(x * 0.70710678118654752440f));
}
__device__ __forceinline__ float wave_sum(float v){
  #pragma unroll
  for (int off = 32; off; off >>= 1) v += __shfl_xor(v, off);
  return v;
}
__device__ __forceinline__ float wave_max(float v){
  #pragma unroll
  for (int off = 32; off; off >>= 1) v = fmaxf(v, __shfl_xor(v, off));
  return v;
}
__device__ __forceinline__ void gload16(const h16* g, h16* l){
  __builtin_amdgcn_global_load_lds(
      (const __attribute__((address_space(1))) void*)g,
      (__attribute__((address_space(3))) void*)l, 16, 0, 0);
}

// ---------------- f32 -> f16 cast ----------------
__global__ __launch_bounds__(256) void k_cast(const float* __restrict__ s,
    h16* __restrict__ d, int n){
  int i = blockIdx.x * 256 + threadIdx.x;
  if (i < n) d[i] = (h16)s[i];
}

// ---------------- conv1 (20->128, k=3) + bn + gelu, LDS tiled ----------------
__global__ __launch_bounds__(256) void k_conv1t(const float* __restrict__ cqcc,
    const float* __restrict__ w, const float* __restrict__ bias,
    const float* __restrict__ g, const float* __restrict__ be,
    const float* __restrict__ mm, const float* __restrict__ vv,
    float* __restrict__ out){
  __shared__ float xs[20][258];
  __shared__ float wsm[32*60];
  const int t0 = blockIdx.x * 256;
  const int ocg = blockIdx.y, b = blockIdx.z;
  const int tid = threadIdx.x;
  for (int idx = tid; idx < 20*258; idx += 256){
    int ic = idx / 258, tt = idx % 258;
    int t = t0 + tt - 1;
    xs[ic][tt] = (t >= 0 && t < TLEN) ? cqcc[((size_t)b*20 + ic)*TLEN + t] : 0.f;
  }
  for (int idx = tid; idx < 32*60; idx += 256)
    wsm[idx] = w[ocg*32*60 + idx];
  __syncthreads();
  int t = t0 + tid;
  if (t >= TLEN) return;
  float acc[32] = {};
  for (int ic = 0; ic < 20; ++ic){
    float x0 = xs[ic][tid], x1v = xs[ic][tid+1], x2v = xs[ic][tid+2];
    #pragma unroll
    for (int oc = 0; oc < 32; ++oc){
      const float* wp = &wsm[(oc*20 + ic)*3];
      acc[oc] += wp[0]*x0 + wp[1]*x1v + wp[2]*x2v;
    }
  }
  #pragma unroll 4
  for (int oc = 0; oc < 32; ++oc){
    int c = ocg*32 + oc;
    float s = rsqrtf(vv[c] + 1e-5f) * g[c];
    float val = (acc[oc] + bias[c] - mm[c]) * s + be[c];
    out[((size_t)b*128 + c)*TLEN + t] = gelu_f(val);
  }
}

// ---------------- im2col for conv2: x1[b][128][2000] -> A2[16000][384] f16 ---
__global__ __launch_bounds__(256) void k_im2col(const float* __restrict__ x1,
    h16* __restrict__ A2){
  int idx = blockIdx.x * 256 + threadIdx.x;
  if (idx >= 16000*384) return;
  int c = idx % 384, m = idx / 384;
  int b = m / TLEN, t = m % TLEN;
  int ic = c / 3, kh = c % 3;
  int ts = t + kh - 1;
  float v = (ts < 0 || ts >= TLEN) ? 0.f : x1[((size_t)b*128 + ic)*TLEN + ts];
  A2[idx] = (h16)v;
}

// ---------------- BN epilogue constants for conv2 ----------------
__global__ void k_bnprep(const float* __restrict__ cb, const float* __restrict__ g,
    const float* __restrict__ be, const float* __restrict__ m,
    const float* __restrict__ v, float* __restrict__ sc, float* __restrict__ off){
  int i = blockIdx.x * 256 + threadIdx.x;
  if (i >= DD) return;
  float s = g[i] * rsqrtf(v[i] + 1e-5f);
  sc[i] = s;
  off[i] = (cb[i] - m[i]) * s + be[i];
}

// ---------------- interp (2000->1024) on [b][t][768] layout + pos ----------
__global__ __launch_bounds__(256) void k_interp2(const float* __restrict__ x2,
    const float* __restrict__ pe, float* __restrict__ cq){
  int idx = blockIdx.x * 256 + threadIdx.x;
  if (idx >= BBATCH * NSEQ * DD) return;
  int d = idx % DD; int i = (idx / DD) % NSEQ; int b = idx / (DD * NSEQ);
  float p = (i + 0.5f) * ((float)TLEN / (float)NSEQ) - 0.5f;
  p = fminf(fmaxf(p, 0.f), (float)(TLEN - 1));
  int lo = (int)floorf(p);
  int hi = min(lo + 1, TLEN - 1);
  float w = p - (float)lo;
  const float* base = x2 + (size_t)b * TLEN * DD + d;
  float val = base[(size_t)lo * DD] * (1.f - w) + base[(size_t)hi * DD] * w;
  cq[idx] = val + pe[(size_t)i * DD + d];
}

__global__ __launch_bounds__(256) void k_addpos(const float* __restrict__ x,
    const float* __restrict__ pe, float* __restrict__ y){
  int idx = blockIdx.x * 256 + threadIdx.x;
  if (idx >= BBATCH * NSEQ * DD) return;
  int d = idx % DD; int i = (idx / DD) % NSEQ;
  y[idx] = x[idx] + pe[(size_t)i * DD + d];
}

// ---------------- layernorm 768, optional ctx add, dual outputs ----------
__global__ __launch_bounds__(256) void k_ln2(const float* __restrict__ in,
    const float* __restrict__ ctx, const float* __restrict__ g,
    const float* __restrict__ be, float* __restrict__ outf, h16* __restrict__ outh){
  __shared__ float ss[4], sqq[4];
  int row = blockIdx.x, tid = threadIdx.x;
  const float* ip = in + (size_t)row * DD;
  int b = row >> 10;
  float v[3]; float s = 0.f, sq = 0.f;
  #pragma unroll
  for (int j = 0; j < 3; ++j){
    int d = j * 256 + tid;
    float x = ip[d];
    if (ctx) x += ctx[b * DD + d];
    v[j] = x; s += x; sq += x * x;
  }
  s = wave_sum(s); sq = wave_sum(sq);
  int w = tid >> 6;
  if ((tid & 63) == 0){ ss[w] = s; sqq[w] = sq; }
  __syncthreads();
  s  = ss[0] + ss[1] + ss[2] + ss[3];
  sq = sqq[0] + sqq[1] + sqq[2] + sqq[3];
  float mean = s * (1.f / DD);
  float var  = sq * (1.f / DD) - mean * mean;
  float r = rsqrtf(var + 1e-5f);
  #pragma unroll
  for (int j = 0; j < 3; ++j){
    int d = j * 256 + tid;
    float y = (v[j] - mean) * r * g[d] + be[d];
    if (outf) outf[(size_t)row * DD + d] = y;
    if (outh) outh[(size_t)row * DD + d] = (h16)y;
  }
}

// ---------------- f16 MFMA GEMM, double-buffered prefetch (2-phase) ----------
// C[M,N] = A[M,K] @ W[N,K]^T. BM=128, BN=64, BK=64, 4 waves (2x2).
// global_load_lds(16B) into linear LDS, inverse-XOR-swizzled global source,
// XOR-swizzled ds_read (bank-conflict-free, verified 0 conflicts).
// Batched via z-decode: base = (z>>2)*s_hi + (z&3)*s_lo.
template<int BN>
__global__ __launch_bounds__(256) void k_gemm_h(
    const h16* __restrict__ A, const h16* __restrict__ W,
    long long sA_hi, long long sA_lo, long long sW_hi, long long sW_lo,
    long long sC_hi, long long sC_lo,
    int lda, int ldw, int ldc, int K, int bzs,
    const float* __restrict__ bias, const float* __restrict__ sc,
    const float* __restrict__ off,
    const h16* __restrict__ addh, float* __restrict__ outf, h16* __restrict__ outh)
{
  __shared__ h16 Als[2][128*64];
  __shared__ h16 Bls[2][BN*64];
  const int tid = threadIdx.x;
  const int z = blockIdx.z, zh = z >> 2, zl = z & 3;
  const size_t aBase = (size_t)(zh * sA_hi + zl * sA_lo);
  const size_t wBase = (size_t)(zh * sW_hi + zl * sW_lo);
  const size_t cBase = (size_t)(zh * sC_hi + zl * sC_lo);
  const int n0 = blockIdx.x * BN, m0 = blockIdx.y * 128;
  const int lane = tid & 63, wid = tid >> 6;
  const int wr = wid >> 1, wc = wid & 1;
  const int lr = lane & 15, lg = lane >> 4;
  constexpr int NR = BN / 32;
  f32x4 acc[4][NR] = {};
  const h16* Ab = A + aBase;
  const h16* Wb = W + wBase;
  auto stage = [&](int buf, int kt){
    #pragma unroll
    for (int i = 0; i < 4; ++i){
      int p = i*256 + tid;
      int row = p >> 3;
      int ch = (p & 7) ^ (row & 7);
      gload16(Ab + (size_t)(m0+row)*lda + kt + ch*8, &Als[buf][p*8]);
    }
    #pragma unroll
    for (int i = 0; i < BN/32; ++i){
      int p = i*256 + tid;
      int row = p >> 3;
      int ch = (p & 7) ^ (row & 7);
      gload16(Wb + (size_t)(n0+row)*ldw + kt + ch*8, &Bls[buf][p*8]);
    }
  };
  stage(0, 0);
  __syncthreads();                       // drain prologue staging
  const int nk = K >> 6;
  for (int t = 0; t < nk; ++t){
    const int cur = t & 1;
    if (t + 1 < nk) stage(cur ^ 1, (t + 1) << 6);   // prefetch next tile first
    #pragma unroll
    for (int kk = 0; kk < 2; ++kk){
      half8v af[4], bf[NR];
      #pragma unroll
      for (int mi = 0; mi < 4; ++mi){
        int row = wr*64 + mi*16 + lr;
        int chp = (kk*4 + lg) ^ (row & 7);
        af[mi] = *(const half8v*)&Als[cur][row*64 + chp*8];
      }
      #pragma unroll
      for (int ni = 0; ni < NR; ++ni){
        int row = wc*(BN/2) + ni*16 + lr;
        int chp = (kk*4 + lg) ^ (row & 7);
        bf[ni] = *(const half8v*)&Bls[cur][row*64 + chp*8];
      }
      #pragma unroll
      for (int mi = 0; mi < 4; ++mi)
        #pragma unroll
        for (int ni = 0; ni < NR; ++ni)
          acc[mi][ni] = __builtin_amdgcn_mfma_f32_16x16x32_f16(af[mi], bf[ni], acc[mi][ni], 0, 0, 0);
    }
    __syncthreads();                     // waits prefetch (vmcnt0) + reads done
  }
  #pragma unroll
  for (int mi = 0; mi < 4; ++mi){
    #pragma unroll
    for (int ni = 0; ni < NR; ++ni){
      int col = n0 + wc*(BN/2) + ni*16 + lr;
      int rowb = m0 + wr*64 + mi*16 + lg*4;
      float cb = bias ? bias[zl*bzs + col] : 0.f;
      #pragma unroll
      for (int r = 0; r < 4; ++r){
        int row = rowb + r;
        size_t idx = cBase + (size_t)row * ldc + col;
        float v = acc[mi][ni][r];
        if (sc){ v = v * sc[col] + off[col]; v = gelu_f(v); }
        else v += cb;
        if (addh) v += (float)addh[idx];
        if (outf) outf[idx] = v;
        if (outh) outh[idx] = (h16)v;
      }
    }
  }
}

// ---------------- V transpose: V[b][q][h*ldv-part] -> VT[bh][d][q] -----------
__global__ __launch_bounds__(256) void k_trV(const h16* __restrict__ Vh, int ldv,
    h16* __restrict__ VT){
  __shared__ h16 tile[32][36];
  const int z = blockIdx.z, b = z >> 2, h = z & 3;
  const int q0 = blockIdx.x * 32, d0 = blockIdx.y * 32;
  const int t = threadIdx.x;
  {
    int qq = t >> 3, dg = (t & 7) * 4;
    const h16* src = Vh + ((size_t)b*NSEQ + q0 + qq)*ldv + h*HDIM + d0 + dg;
    half4v v = *(const half4v*)src;
    *(half4v*)&tile[qq][dg] = v;
  }
  __syncthreads();
  {
    int dd = t >> 3, qg = (t & 7) * 4;
    half4v ov;
    ov[0] = tile[qg+0][dd]; ov[1] = tile[qg+1][dd];
    ov[2] = tile[qg+2][dd]; ov[3] = tile[qg+3][dd];
    *(half4v*)(VT + (size_t)z*HDIM*NSEQ + (size_t)(d0+dd)*NSEQ + q0 + qg) = ov;
  }
}

// ------------- softmax over S rows, vectorized: 2 rows/block -----------------
__global__ __launch_bounds__(256) void k_softmax_s(h16* __restrict__ S){
  __shared__ float redm[4], reds[4];
  const float SCALE = 0.07216878364870322f;  // 1/sqrt(192)
  const int tid = threadIdx.x;
  const int r = tid >> 7, t = tid & 127;
  h16* p = S + (size_t)(blockIdx.x*2 + r) * 1024 + t*8;
  half8v v = *(const half8v*)p;
  float f[8]; float mx = -1e30f;
  #pragma unroll
  for (int j = 0; j < 8; ++j){ f[j] = (float)v[j] * SCALE; mx = fmaxf(mx, f[j]); }
  mx = wave_max(mx);
  int w = tid >> 6;
  if ((tid & 63) == 0) redm[w] = mx;
  __syncthreads();
  mx = fmaxf(redm[r*2], redm[r*2+1]);
  float s = 0.f;
  #pragma unroll
  for (int j = 0; j < 8; ++j){ f[j] = __expf(f[j] - mx); s += f[j]; }
  s = wave_sum(s);
  if ((tid & 63) == 0) reds[w] = s;
  __syncthreads();
  float inv = 1.0f / (reds[r*2] + reds[r*2+1]);
  half8v o;
  #pragma unroll
  for (int j = 0; j < 8; ++j) o[j] = (h16)(f[j] * inv);
  *(half8v*)p = o;
}

// ---------------- GAT helpers ----------------
__global__ __launch_bounds__(128) void k_rowdot(const h16* __restrict__ h,
    const float* __restrict__ aw, float* __restrict__ sj){
  __shared__ float red[2];
  int row = blockIdx.x, tid = threadIdx.x;
  float s = 0.f;
  if (tid < 96){
    half8v v = *(const half8v*)(h + (size_t)row * DD + tid*8);
    #pragma unroll
    for (int j = 0; j < 8; ++j) s += (float)v[j] * aw[tid*8 + j];
  }
  s = wave_sum(s);
  if ((tid & 63) == 0) red[tid >> 6] = s;
  __syncthreads();
  if (tid == 0) sj[row] = red[0] + red[1];
}

__global__ __launch_bounds__(256) void k_softmax1024(const float* __restrict__ x,
    float* __restrict__ y){
  __shared__ float red[4];
  int b = blockIdx.x, tid = threadIdx.x;
  const float* ip = x + b * NSEQ;
  float v[4]; float mx = -1e30f;
  #pragma unroll
  for (int j = 0; j < 4; ++j){ v[j] = ip[j * 256 + tid]; mx = fmaxf(mx, v[j]); }
  mx = wave_max(mx);
  if ((tid & 63) == 0) red[tid >> 6] = mx;
  __syncthreads();
  mx = fmaxf(fmaxf(red[0], red[1]), fmaxf(red[2], red[3]));
  __syncthreads();
  float s = 0.f;
  #pragma unroll
  for (int j = 0; j < 4; ++j){ v[j] = __expf(v[j] - mx); s += v[j]; }
  s = wave_sum(s);
  if ((tid & 63) == 0) red[tid >> 6] = s;
  __syncthreads();
  s = red[0] + red[1] + red[2] + red[3];
  float inv = 1.0f / s;
  #pragma unroll
  for (int j = 0; j < 4; ++j) y[b * NSEQ + j * 256 + tid] = v[j] * inv;
}

// ctx two-stage: stage1 partial over 64-j chunks, stage2 combine
__global__ __launch_bounds__(256) void k_ctx1(const float* __restrict__ alpha,
    const h16* __restrict__ h, float* __restrict__ part){
  int d = blockIdx.x * 256 + threadIdx.x;
  int b = blockIdx.y, pc = blockIdx.z;
  if (d >= DD) return;
  float acc = 0.f;
  const h16* hp = h + ((size_t)b * NSEQ + pc * 64) * DD + d;
  const float* ap = alpha + b * NSEQ + pc * 64;
  #pragma unroll 4
  for (int j = 0; j < 64; ++j) acc += ap[j] * (float)hp[(size_t)j * DD];
  part[(size_t)(b * 16 + pc) * DD + d] = acc;
}
__global__ __launch_bounds__(256) void k_ctx2(const float* __restrict__ part,
    float scale, float* __restrict__ ctx){
  int d = blockIdx.x * 256 + threadIdx.x;
  int b = blockIdx.y;
  if (d >= DD) return;
  float acc = 0.f;
  #pragma unroll
  for (int p = 0; p < 16; ++p) acc += part[(size_t)(b * 16 + p) * DD + d];
  ctx[b * DD + d] = acc * scale;
}

// pool two-stage (f32 input)
__global__ __launch_bounds__(256) void k_pool1(const float* __restrict__ x,
    float* __restrict__ part){
  int d = blockIdx.x * 256 + threadIdx.x;
  int b = blockIdx.y, pc = blockIdx.z;
  if (d >= DD) return;
  float acc = 0.f;
  const float* xp = x + ((size_t)b * NSEQ + pc * 64) * DD + d;
  #pragma unroll 4
  for (int j = 0; j < 64; ++j) acc += xp[(size_t)j * DD];
  part[(size_t)(b * 16 + pc) * DD + d] = acc;
}

__global__ __launch_bounds__(128) void k_clf(const float* __restrict__ pooled,
    const float* __restrict__ w1, const float* __restrict__ b1,
    const float* __restrict__ w2, const float* __restrict__ b2,
    float* __restrict__ out){
  __shared__ float pl[DD];
  __shared__ float h1[128];
  int b = blockIdx.x, tid = threadIdx.x;
  #pragma unroll
  for (int j = 0; j < 6; ++j) pl[j * 128 + tid] = pooled[b * DD + j * 128 + tid];
  __syncthreads();
  float acc = b1[tid];
  const float* wp = w1 + (size_t)tid * DD;
  for (int d = 0; d < DD; ++d) acc += pl[d] * wp[d];
  h1[tid] = gelu_f(acc);
  __syncthreads();
  if (tid < 2){
    float o = b2[tid];
    const float* w2p = w2 + tid * 128;
    for (int c = 0; c < 128; ++c) o += h1[c] * w2p[c];
    out[b * 2 + tid] = o;
  }
}

// =========================== launcher ===========================
static void gemmN(hipStream_t s, const h16* A, const h16* W, int M, int N, int K,
                  int lda, int ldw, int ldc, int Z,
                  long long sAh, long long sAl, long long sWh, long long sWl,
                  long long sCh, long long sCl, int bzs,
                  const float* bias, const float* sc, const float* off,
                  const h16* addh, float* outf, h16* outh){
  dim3 g(N/64, M/128, Z);
  k_gemm_h<64><<<g, 256, 0, s>>>(A, W, sAh, sAl, sWh, sWl, sCh, sCl,
                                 lda, ldw, ldc, K, bzs, bias, sc, off, addh, outf, outh);
}

extern "C" void kernel_launch(void* const* d_in, const int* in_sizes, int n_in,
                              void* d_out, int out_size, void* d_ws, size_t ws_size,
                              hipStream_t stream){
  (void)in_sizes; (void)n_in; (void)out_size;
  const float* w2v      = (const float*)d_in[0];
  const float* cqcc     = (const float*)d_in[1];
  const float* conv1_w  = (const float*)d_in[2];
  const float* conv1_b  = (const float*)d_in[3];
  const float* bn1_g    = (const float*)d_in[4];
  const float* bn1_b    = (const float*)d_in[5];
  const float* bn1_m    = (const float*)d_in[6];
  const float* bn1_v    = (const float*)d_in[7];
  const float* conv2_w  = (const float*)d_in[8];
  const float* conv2_b  = (const float*)d_in[9];
  const float* bn2_g    = (const float*)d_in[10];
  const float* bn2_b    = (const float*)d_in[11];
  const float* bn2_m    = (const float*)d_in[12];
  const float* bn2_v    = (const float*)d_in[13];
  const float* pos_embed= (const float*)d_in[14];
  const float* lnq_g    = (const float*)d_in[15];
  const float* lnq_b    = (const float*)d_in[16];
  const float* lnkv_g   = (const float*)d_in[17];
  const float* lnkv_b   = (const float*)d_in[18];
  const float* a1_in_w  = (const float*)d_in[19];
  const float* a1_in_b  = (const float*)d_in[20];
  const float* a1_out_w = (const float*)d_in[21];
  const float* a1_out_b = (const float*)d_in[22];
  const float* a2_in_w  = (const float*)d_in[23];
  const float* a2_in_b  = (const float*)d_in[24];
  const float* a2_out_w = (const float*)d_in[25];
  const float* a2_out_b = (const float*)d_in[26];
  const float* gat_fc_w = (const float*)d_in[27];
  const float* gat_fc_b = (const float*)d_in[28];
  const float* gat_a_w  = (const float*)d_in[29];
  // d_in[30] gat_a_b: cancels in softmax over j — unused.
  const float* gln_g    = (const float*)d_in[31];
  const float* gln_b    = (const float*)d_in[32];
  const float* clf_w1   = (const float*)d_in[33];
  const float* clf_b1   = (const float*)d_in[34];
  const float* clf_w2   = (const float*)d_in[35];
  const float* clf_b2   = (const float*)d_in[36];

  char* wsp = (char*)d_ws;
  auto F = [&](size_t bytes){ char* p = wsp; wsp += (bytes + 255) & ~(size_t)255; return p; };
  float* Abuf = (float*)F(25165824);        // cq  -> later xb (f32)
  float* Bbuf = (float*)F(25165824);        // wpl -> later xh (f16 half)
  h16* L1   = (h16*)F(12582912);            // LN out / Ob
  h16* L2   = (h16*)F(12582912);            // LN out / o1h
  h16* Qh   = (h16*)F(12582912);            // Q / gat h
  h16* KVh  = (h16*)F(25165824);            // K|V interleaved [8192][1536]
  h16* VT   = (h16*)F(12582912);            // V^T (also L4 LN buf)
  h16* Sb   = (h16*)F(67108864);            // scores (also x2f f32)
  h16* w_a1in  = (h16*)F(3538944);
  h16* w_a1out = (h16*)F(1179648);
  h16* w_a2in  = (h16*)F(3538944);
  h16* w_a2out = (h16*)F(1179648);
  h16* w_gat   = (h16*)F(3538944);
  h16* w_c2    = (h16*)F(589824);
  float* scb   = (float*)F(3072);
  float* offb  = (float*)F(3072);
  float* sj    = (float*)F(32768);
  float* alpha = (float*)F(32768);
  float* ctxb  = (float*)F(24576);
  float* pooled= (float*)F(24576);
  float* partb = (float*)F(393216);         // ctx/pool partials 8*16*768 f32
  if ((size_t)(wsp - (char*)d_ws) > ws_size) return;

  float* x1  = (float*)KVh;            // conv1 out (f32, 8.2 MB)
  h16*   A2  = KVh + 6291456;          // im2col buffer (12.3 MB, 2nd half)
  float* x2f = (float*)Sb;             // conv2 out f32 [b][t][768]
  h16*   o1h = L2;                     // MHA1 output (f16)
  h16*   L4  = VT;                     // LNkv(cq) for MHA2
  h16*   Ob  = L1;                     // attention output (f16)
  float* xb  = Abuf;                   // GAT running state f32
  h16*   xh  = (h16*)Bbuf;             // f16 copy of xb
  h16*   hh  = Qh;                     // GAT h

  const size_t S = (size_t)BBATCH * NSEQ * DD;
  const int EW = (int)((S + 255) / 256);
  const long long PH = (long long)NSEQ * DD;       // per-batch elems
  const long long SS = (long long)NSEQ * NSEQ;
  const long long PKV = (long long)NSEQ * 1536;    // per-batch elems in KVh
  const long long HV = (long long)HDIM * NSEQ;

  // --- weight casts + bn prep ---
  k_cast<<<(1769472+255)/256, 256, 0, stream>>>(a1_in_w,  w_a1in,  1769472);
  k_cast<<<(589824+255)/256,  256, 0, stream>>>(a1_out_w, w_a1out, 589824);
  k_cast<<<(1769472+255)/256, 256, 0, stream>>>(a2_in_w,  w_a2in,  1769472);
  k_cast<<<(589824+255)/256,  256, 0, stream>>>(a2_out_w, w_a2out, 589824);
  k_cast<<<(1769472+255)/256, 256, 0, stream>>>(gat_fc_w, w_gat,   1769472);
  k_cast<<<(294912+255)/256,  256, 0, stream>>>(conv2_w,  w_c2,    294912);
  k_bnprep<<<3, 256, 0, stream>>>(conv2_b, bn2_g, bn2_b, bn2_m, bn2_v, scb, offb);

  // --- front-end convs ---
  k_conv1t<<<dim3(8, 4, BBATCH), 256, 0, stream>>>(cqcc, conv1_w, conv1_b,
      bn1_g, bn1_b, bn1_m, bn1_v, x1);
  k_im2col<<<(16000*384+255)/256, 256, 0, stream>>>(x1, A2);
  gemmN(stream, A2, w_c2, 16000, DD, 384, 384, 384, DD, 1,
        0,0,0,0,0,0, 0, nullptr, scb, offb, nullptr, x2f, nullptr);
  k_interp2<<<EW, 256, 0, stream>>>(x2f, pos_embed, Abuf);
  k_addpos<<<EW, 256, 0, stream>>>(w2v, pos_embed, Bbuf);

  const int NR = BBATCH * NSEQ;  // 8192 rows

  // ================= MHA1: q = LNq(cq), kv = LNkv(w) =================
  k_ln2<<<NR, 256, 0, stream>>>(Abuf, nullptr, lnq_g,  lnq_b,  nullptr, L1);
  k_ln2<<<NR, 256, 0, stream>>>(Bbuf, nullptr, lnkv_g, lnkv_b, nullptr, L2);
  gemmN(stream, L1, w_a1in, NR, DD, DD, DD, DD, DD, 1, 0,0,0,0,0,0, 0,
        a1_in_b, nullptr, nullptr, nullptr, nullptr, Qh);
  gemmN(stream, L2, w_a1in + 589824, NR, DD, DD, DD, DD, 1536, 2,
        0,0, 0,589824, 0,768, DD,
        a1_in_b + DD, nullptr, nullptr, nullptr, nullptr, KVh);
  k_trV<<<dim3(32, 6, 32), 256, 0, stream>>>(KVh + 768, 1536, VT);
  gemmN(stream, Qh, KVh, NSEQ, NSEQ, HDIM, DD, 1536, NSEQ, 32,
        PH, HDIM, PKV, HDIM, 4*SS, SS, 0,
        nullptr, nullptr, nullptr, nullptr, nullptr, Sb);
  k_softmax_s<<<16*NSEQ, 256, 0, stream>>>(Sb);
  gemmN(stream, Sb, VT, NSEQ, HDIM, NSEQ, NSEQ, NSEQ, DD, 32,
        4*SS, SS, 4*HV, HV, PH, HDIM, 0,
        nullptr, nullptr, nullptr, nullptr, nullptr, Ob);
  gemmN(stream, Ob, w_a1out, NR, DD, DD, DD, DD, DD, 1, 0,0,0,0,0,0, 0,
        a1_out_b, nullptr, nullptr, nullptr, nullptr, o1h);

  // ================= MHA2: q = LNq(w), kv = LNkv(cq) =================
  k_ln2<<<NR, 256, 0, stream>>>(Bbuf, nullptr, lnq_g,  lnq_b,  nullptr, L1);
  k_ln2<<<NR, 256, 0, stream>>>(Abuf, nullptr, lnkv_g, lnkv_b, nullptr, L4);
  gemmN(stream, L1, w_a2in, NR, DD, DD, DD, DD, DD, 1, 0,0,0,0,0,0, 0,
        a2_in_b, nullptr, nullptr, nullptr, nullptr, Qh);
  gemmN(stream, L4, w_a2in + 589824, NR, DD, DD, DD, DD, 1536, 2,
        0,0, 0,589824, 0,768, DD,
        a2_in_b + DD, nullptr, nullptr, nullptr, nullptr, KVh);
  k_trV<<<dim3(32, 6, 32), 256, 0, stream>>>(KVh + 768, 1536, VT);
  gemmN(stream, Qh, KVh, NSEQ, NSEQ, HDIM, DD, 1536, NSEQ, 32,
        PH, HDIM, PKV, HDIM, 4*SS, SS, 0,
        nullptr, nullptr, nullptr, nullptr, nullptr, Sb);
  k_softmax_s<<<16*NSEQ, 256, 0, stream>>>(Sb);
  gemmN(stream, Sb, VT, NSEQ, HDIM, NSEQ, NSEQ, NSEQ, DD, 32,
        4*SS, SS, 4*HV, HV, PH, HDIM, 0,
        nullptr, nullptr, nullptr, nullptr, nullptr, Ob);
  // out-proj2 + add out1 -> xb (f32) and xh (f16)
  gemmN(stream, Ob, w_a2out, NR, DD, DD, DD, DD, DD, 1, 0,0,0,0,0,0, 0,
        a2_out_b, nullptr, nullptr, o1h, xb, xh);

  // ================= GAT x3 (softmax over j collapses) =================
  for (int l = 0; l < 3; ++l){
    gemmN(stream, xh, w_gat + (size_t)l*589824, NR, DD, DD, DD, DD, DD, 1,
          0,0,0,0,0,0, 0, gat_fc_b + l*DD, nullptr, nullptr, nullptr, nullptr, hh);
    k_rowdot<<<NR, 128, 0, stream>>>(hh, gat_a_w + l*2*DD + DD, sj);
    k_softmax1024<<<BBATCH, 256, 0, stream>>>(sj, alpha);
    k_ctx1<<<dim3(3, BBATCH, 16), 256, 0, stream>>>(alpha, hh, partb);
    k_ctx2<<<dim3(3, BBATCH), 256, 0, stream>>>(partb, 1.0f, ctxb);
    k_ln2<<<NR, 256, 0, stream>>>(xb, ctxb, gln_g + l*DD, gln_b + l*DD, xb, xh);
  }

  k_pool1<<<dim3(3, BBATCH, 16), 256, 0, stream>>>(xb, partb);
  k_ctx2<<<dim3(3, BBATCH), 256, 0, stream>>>(partb, 1.0f/NSEQ, pooled);
  k_clf<<<BBATCH, 128, 0, stream>>>(pooled, clf_w1, clf_b1, clf_w2, clf_b2,
                                    (float*)d_out);
}

// Round 5
// 726.453 us; speedup vs baseline: 8.6311x; 1.1635x over previous
//
#include <hip/hip_runtime.h>
#include <math.h>

#define DD 768
#define NH 4
#define HDIM 192
#define BBATCH 8
#define NSEQ 1024
#define TLEN 2000

typedef _Float16 h16;
typedef _Float16 half8v __attribute__((ext_vector_type(8)));
typedef _Float16 half4v __attribute__((ext_vector_type(4)));
typedef float f32x4 __attribute__((ext_vector_type(4)));

__device__ __forceinline__ float gelu_f(float x){
  return 0.5f * x * (1.0f + erff(x * 0.70710678118654752440f));
}
__device__ __forceinline__ float wave_sum(float v){
  #pragma unroll
  for (int off = 32; off; off >>= 1) v += __shfl_xor(v, off);
  return v;
}
__device__ __forceinline__ float wave_max(float v){
  #pragma unroll
  for (int off = 32; off; off >>= 1) v = fmaxf(v, __shfl_xor(v, off));
  return v;
}
__device__ __forceinline__ void gload16(const h16* g, h16* l){
  __builtin_amdgcn_global_load_lds(
      (const __attribute__((address_space(1))) void*)g,
      (__attribute__((address_space(3))) void*)l, 16, 0, 0);
}

// ---------------- f32 -> f16 cast ----------------
__global__ __launch_bounds__(256) void k_cast(const float* __restrict__ s,
    h16* __restrict__ d, int n){
  int i = blockIdx.x * 256 + threadIdx.x;
  if (i < n) d[i] = (h16)s[i];
}

// ---------------- conv1 (20->128, k=3) + bn + gelu, LDS tiled ----------------
__global__ __launch_bounds__(256) void k_conv1t(const float* __restrict__ cqcc,
    const float* __restrict__ w, const float* __restrict__ bias,
    const float* __restrict__ g, const float* __restrict__ be,
    const float* __restrict__ mm, const float* __restrict__ vv,
    float* __restrict__ out){
  __shared__ float xs[20][258];
  __shared__ float wsm[32*60];
  const int t0 = blockIdx.x * 256;
  const int ocg = blockIdx.y, b = blockIdx.z;
  const int tid = threadIdx.x;
  for (int idx = tid; idx < 20*258; idx += 256){
    int ic = idx / 258, tt = idx % 258;
    int t = t0 + tt - 1;
    xs[ic][tt] = (t >= 0 && t < TLEN) ? cqcc[((size_t)b*20 + ic)*TLEN + t] : 0.f;
  }
  for (int idx = tid; idx < 32*60; idx += 256)
    wsm[idx] = w[ocg*32*60 + idx];
  __syncthreads();
  int t = t0 + tid;
  if (t >= TLEN) return;
  float acc[32] = {};
  for (int ic = 0; ic < 20; ++ic){
    float x0 = xs[ic][tid], x1v = xs[ic][tid+1], x2v = xs[ic][tid+2];
    #pragma unroll
    for (int oc = 0; oc < 32; ++oc){
      const float* wp = &wsm[(oc*20 + ic)*3];
      acc[oc] += wp[0]*x0 + wp[1]*x1v + wp[2]*x2v;
    }
  }
  #pragma unroll 4
  for (int oc = 0; oc < 32; ++oc){
    int c = ocg*32 + oc;
    float s = rsqrtf(vv[c] + 1e-5f) * g[c];
    float val = (acc[oc] + bias[c] - mm[c]) * s + be[c];
    out[((size_t)b*128 + c)*TLEN + t] = gelu_f(val);
  }
}

// ---------------- im2col for conv2: x1[b][128][2000] -> A2[16000][384] f16 ---
__global__ __launch_bounds__(256) void k_im2col(const float* __restrict__ x1,
    h16* __restrict__ A2){
  int idx = blockIdx.x * 256 + threadIdx.x;
  if (idx >= 16000*384) return;
  int c = idx % 384, m = idx / 384;
  int b = m / TLEN, t = m % TLEN;
  int ic = c / 3, kh = c % 3;
  int ts = t + kh - 1;
  float v = (ts < 0 || ts >= TLEN) ? 0.f : x1[((size_t)b*128 + ic)*TLEN + ts];
  A2[idx] = (h16)v;
}

// ---------------- BN epilogue constants for conv2 ----------------
__global__ void k_bnprep(const float* __restrict__ cb, const float* __restrict__ g,
    const float* __restrict__ be, const float* __restrict__ m,
    const float* __restrict__ v, float* __restrict__ sc, float* __restrict__ off){
  int i = blockIdx.x * 256 + threadIdx.x;
  if (i >= DD) return;
  float s = g[i] * rsqrtf(v[i] + 1e-5f);
  sc[i] = s;
  off[i] = (cb[i] - m[i]) * s + be[i];
}

// ---------------- interp (2000->1024) on [b][t][768] layout + pos ----------
__global__ __launch_bounds__(256) void k_interp2(const float* __restrict__ x2,
    const float* __restrict__ pe, float* __restrict__ cq){
  int idx = blockIdx.x * 256 + threadIdx.x;
  if (idx >= BBATCH * NSEQ * DD) return;
  int d = idx % DD; int i = (idx / DD) % NSEQ; int b = idx / (DD * NSEQ);
  float p = (i + 0.5f) * ((float)TLEN / (float)NSEQ) - 0.5f;
  p = fminf(fmaxf(p, 0.f), (float)(TLEN - 1));
  int lo = (int)floorf(p);
  int hi = min(lo + 1, TLEN - 1);
  float w = p - (float)lo;
  const float* base = x2 + (size_t)b * TLEN * DD + d;
  float val = base[(size_t)lo * DD] * (1.f - w) + base[(size_t)hi * DD] * w;
  cq[idx] = val + pe[(size_t)i * DD + d];
}

__global__ __launch_bounds__(256) void k_addpos(const float* __restrict__ x,
    const float* __restrict__ pe, float* __restrict__ y){
  int idx = blockIdx.x * 256 + threadIdx.x;
  if (idx >= BBATCH * NSEQ * DD) return;
  int d = idx % DD; int i = (idx / DD) % NSEQ;
  y[idx] = x[idx] + pe[(size_t)i * DD + d];
}

// ---------------- layernorm 768, optional ctx add, f32+f16 outputs ----------
__global__ __launch_bounds__(256) void k_ln2(const float* __restrict__ in,
    const float* __restrict__ ctx, const float* __restrict__ g,
    const float* __restrict__ be, float* __restrict__ outf, h16* __restrict__ outh){
  __shared__ float ss[4], sqq[4];
  int row = blockIdx.x, tid = threadIdx.x;
  const float* ip = in + (size_t)row * DD;
  int b = row >> 10;
  float v[3]; float s = 0.f, sq = 0.f;
  #pragma unroll
  for (int j = 0; j < 3; ++j){
    int d = j * 256 + tid;
    float x = ip[d];
    if (ctx) x += ctx[b * DD + d];
    v[j] = x; s += x; sq += x * x;
  }
  s = wave_sum(s); sq = wave_sum(sq);
  int w = tid >> 6;
  if ((tid & 63) == 0){ ss[w] = s; sqq[w] = sq; }
  __syncthreads();
  s  = ss[0] + ss[1] + ss[2] + ss[3];
  sq = sqq[0] + sqq[1] + sqq[2] + sqq[3];
  float mean = s * (1.f / DD);
  float var  = sq * (1.f / DD) - mean * mean;
  float r = rsqrtf(var + 1e-5f);
  #pragma unroll
  for (int j = 0; j < 3; ++j){
    int d = j * 256 + tid;
    float y = (v[j] - mean) * r * g[d] + be[d];
    if (outf) outf[(size_t)row * DD + d] = y;
    if (outh) outh[(size_t)row * DD + d] = (h16)y;
  }
}

// ---------------- dual layernorm: one read, two (g,b) variants --------------
__global__ __launch_bounds__(256) void k_ln2two(const float* __restrict__ in,
    const float* __restrict__ g1, const float* __restrict__ b1, h16* __restrict__ o1,
    const float* __restrict__ g2, const float* __restrict__ b2, h16* __restrict__ o2){
  __shared__ float ss[4], sqq[4];
  int row = blockIdx.x, tid = threadIdx.x;
  const float* ip = in + (size_t)row * DD;
  float v[3]; float s = 0.f, sq = 0.f;
  #pragma unroll
  for (int j = 0; j < 3; ++j){
    int d = j * 256 + tid;
    float x = ip[d];
    v[j] = x; s += x; sq += x * x;
  }
  s = wave_sum(s); sq = wave_sum(sq);
  int w = tid >> 6;
  if ((tid & 63) == 0){ ss[w] = s; sqq[w] = sq; }
  __syncthreads();
  s  = ss[0] + ss[1] + ss[2] + ss[3];
  sq = sqq[0] + sqq[1] + sqq[2] + sqq[3];
  float mean = s * (1.f / DD);
  float var  = sq * (1.f / DD) - mean * mean;
  float r = rsqrtf(var + 1e-5f);
  #pragma unroll
  for (int j = 0; j < 3; ++j){
    int d = j * 256 + tid;
    float xn = (v[j] - mean) * r;
    o1[(size_t)row * DD + d] = (h16)(xn * g1[d] + b1[d]);
    o2[(size_t)row * DD + d] = (h16)(xn * g2[d] + b2[d]);
  }
}

// ---------------- f16 MFMA GEMM, double-buffered prefetch (2-phase) ----------
template<int BN>
__global__ __launch_bounds__(256) void k_gemm_h(
    const h16* __restrict__ A, const h16* __restrict__ W,
    long long sA_hi, long long sA_lo, long long sW_hi, long long sW_lo,
    long long sC_hi, long long sC_lo,
    int lda, int ldw, int ldc, int K, int bzs,
    const float* __restrict__ bias, const float* __restrict__ sc,
    const float* __restrict__ off,
    const h16* __restrict__ addh, float* __restrict__ outf, h16* __restrict__ outh)
{
  __shared__ h16 Als[2][128*64];
  __shared__ h16 Bls[2][BN*64];
  const int tid = threadIdx.x;
  const int z = blockIdx.z, zh = z >> 2, zl = z & 3;
  const size_t aBase = (size_t)(zh * sA_hi + zl * sA_lo);
  const size_t wBase = (size_t)(zh * sW_hi + zl * sW_lo);
  const size_t cBase = (size_t)(zh * sC_hi + zl * sC_lo);
  const int n0 = blockIdx.x * BN, m0 = blockIdx.y * 128;
  const int lane = tid & 63, wid = tid >> 6;
  const int wr = wid >> 1, wc = wid & 1;
  const int lr = lane & 15, lg = lane >> 4;
  constexpr int NR = BN / 32;
  f32x4 acc[4][NR] = {};
  const h16* Ab = A + aBase;
  const h16* Wb = W + wBase;
  auto stage = [&](int buf, int kt){
    #pragma unroll
    for (int i = 0; i < 4; ++i){
      int p = i*256 + tid;
      int row = p >> 3;
      int ch = (p & 7) ^ (row & 7);
      gload16(Ab + (size_t)(m0+row)*lda + kt + ch*8, &Als[buf][p*8]);
    }
    #pragma unroll
    for (int i = 0; i < BN/32; ++i){
      int p = i*256 + tid;
      int row = p >> 3;
      int ch = (p & 7) ^ (row & 7);
      gload16(Wb + (size_t)(n0+row)*ldw + kt + ch*8, &Bls[buf][p*8]);
    }
  };
  stage(0, 0);
  __syncthreads();
  const int nk = K >> 6;
  for (int t = 0; t < nk; ++t){
    const int cur = t & 1;
    if (t + 1 < nk) stage(cur ^ 1, (t + 1) << 6);
    #pragma unroll
    for (int kk = 0; kk < 2; ++kk){
      half8v af[4], bf[NR];
      #pragma unroll
      for (int mi = 0; mi < 4; ++mi){
        int row = wr*64 + mi*16 + lr;
        int chp = (kk*4 + lg) ^ (row & 7);
        af[mi] = *(const half8v*)&Als[cur][row*64 + chp*8];
      }
      #pragma unroll
      for (int ni = 0; ni < NR; ++ni){
        int row = wc*(BN/2) + ni*16 + lr;
        int chp = (kk*4 + lg) ^ (row & 7);
        bf[ni] = *(const half8v*)&Bls[cur][row*64 + chp*8];
      }
      #pragma unroll
      for (int mi = 0; mi < 4; ++mi)
        #pragma unroll
        for (int ni = 0; ni < NR; ++ni)
          acc[mi][ni] = __builtin_amdgcn_mfma_f32_16x16x32_f16(af[mi], bf[ni], acc[mi][ni], 0, 0, 0);
    }
    __syncthreads();
  }
  #pragma unroll
  for (int mi = 0; mi < 4; ++mi){
    #pragma unroll
    for (int ni = 0; ni < NR; ++ni){
      int col = n0 + wc*(BN/2) + ni*16 + lr;
      int rowb = m0 + wr*64 + mi*16 + lg*4;
      float cb = bias ? bias[zl*bzs + col] : 0.f;
      #pragma unroll
      for (int r = 0; r < 4; ++r){
        int row = rowb + r;
        size_t idx = cBase + (size_t)row * ldc + col;
        float v = acc[mi][ni][r];
        if (sc){ v = v * sc[col] + off[col]; v = gelu_f(v); }
        else v += cb;
        if (addh) v += (float)addh[idx];
        if (outf) outf[idx] = v;
        if (outh) outh[idx] = (h16)v;
      }
    }
  }
}

// ---------------- V transpose: V[b][q][h-part] -> VT[bh][d][q] ---------------
__global__ __launch_bounds__(256) void k_trV(const h16* __restrict__ Vh, int ldv,
    h16* __restrict__ VT){
  __shared__ h16 tile[32][36];
  const int z = blockIdx.z, b = z >> 2, h = z & 3;
  const int q0 = blockIdx.x * 32, d0 = blockIdx.y * 32;
  const int t = threadIdx.x;
  {
    int qq = t >> 3, dg = (t & 7) * 4;
    const h16* src = Vh + ((size_t)b*NSEQ + q0 + qq)*ldv + h*HDIM + d0 + dg;
    half4v v = *(const half4v*)src;
    *(half4v*)&tile[qq][dg] = v;
  }
  __syncthreads();
  {
    int dd = t >> 3, qg = (t & 7) * 4;
    half4v ov;
    ov[0] = tile[qg+0][dd]; ov[1] = tile[qg+1][dd];
    ov[2] = tile[qg+2][dd]; ov[3] = tile[qg+3][dd];
    *(half4v*)(VT + (size_t)z*HDIM*NSEQ + (size_t)(d0+dd)*NSEQ + q0 + qg) = ov;
  }
}

// ---------------- fused flash attention (MFMA, online softmax) ---------------
// grid (16 q-tiles, 4 heads, 8 batch), 256 threads = 4 waves x 16 q-rows.
// K from KVh ([b][k][1536], head offset), V from VT ([bh][d][1024]).
__global__ __launch_bounds__(256) void k_flash(const h16* __restrict__ Qp,
    const h16* __restrict__ Kp, const h16* __restrict__ VTp,
    h16* __restrict__ Op){
  __shared__ h16 Qs[64*192];
  __shared__ h16 Ks[2][64*192];
  __shared__ h16 Vs[2][192*64];
  __shared__ h16 Ps[4][16*64];
  const int tid = threadIdx.x;
  const int q0 = blockIdx.x * 64, h = blockIdx.y, b = blockIdx.z;
  const h16* Qg = Qp + (size_t)b*NSEQ*DD + h*HDIM;
  const h16* Kg = Kp + (size_t)b*NSEQ*1536 + h*HDIM;
  const h16* Vg = VTp + (size_t)(b*4 + h)*HDIM*NSEQ;
  const int lane = tid & 63, wid = tid >> 6;
  const int lr = lane & 15, lg = lane >> 4;
  #pragma unroll
  for (int i = 0; i < 6; ++i){      // stage Q tile (64x192), swizzled
    int p = i*256 + tid;
    int row = p / 24, chp = p % 24;
    int ch = chp ^ (row & 7);
    gload16(Qg + (size_t)(q0+row)*DD + ch*8, &Qs[p*8]);
  }
  auto stageK = [&](int buf, int k0){
    #pragma unroll
    for (int i = 0; i < 6; ++i){
      int p = i*256 + tid;
      int row = p / 24, chp = p % 24;
      int ch = chp ^ (row & 7);
      gload16(Kg + (size_t)(k0+row)*1536 + ch*8, &Ks[buf][p*8]);
    }
  };
  auto stageV = [&](int buf, int k0){
    #pragma unroll
    for (int i = 0; i < 6; ++i){
      int p = i*256 + tid;
      int row = p >> 3, chp = p & 7;
      int ch = chp ^ (row & 7);
      gload16(Vg + (size_t)row*NSEQ + k0 + ch*8, &Vs[buf][p*8]);
    }
  };
  stageK(0, 0); stageV(0, 0);
  __syncthreads();
  half8v qf[6];
  #pragma unroll
  for (int ks = 0; ks < 6; ++ks){
    int row = wid*16 + lr;
    int ch = (ks*4 + lg) ^ (row & 7);
    qf[ks] = *(const half8v*)&Qs[row*192 + ch*8];
  }
  f32x4 oacc[12] = {};
  float m_run[4] = {-1e30f, -1e30f, -1e30f, -1e30f};
  float l_run[4] = {};
  const float SC = 0.07216878364870322f;   // 1/sqrt(192)
  for (int kt = 0; kt < 16; ++kt){
    const int cur = kt & 1;
    if (kt + 1 < 16){ stageK(cur^1, (kt+1)*64); stageV(cur^1, (kt+1)*64); }
    // S = Q @ K^T  (16 q x 64 keys per wave)
    f32x4 sacc[4] = {};
    #pragma unroll
    for (int ks = 0; ks < 6; ++ks){
      #pragma unroll
      for (int t = 0; t < 4; ++t){
        int krow = t*16 + lr;
        int ch = (ks*4 + lg) ^ (krow & 7);
        half8v kf = *(const half8v*)&Ks[cur][krow*192 + ch*8];
        sacc[t] = __builtin_amdgcn_mfma_f32_16x16x32_f16(qf[ks], kf, sacc[t], 0, 0, 0);
      }
    }
    // online softmax: rows r held across the 16 lanes of group lg
    float mnew[4], c[4], psum[4];
    #pragma unroll
    for (int r = 0; r < 4; ++r){
      float mt = fmaxf(fmaxf(sacc[0][r], sacc[1][r]), fmaxf(sacc[2][r], sacc[3][r]));
      #pragma unroll
      for (int off = 1; off < 16; off <<= 1) mt = fmaxf(mt, __shfl_xor(mt, off));
      mnew[r] = fmaxf(m_run[r], mt * SC);
      c[r] = __expf(m_run[r] - mnew[r]);
      psum[r] = 0.f;
    }
    #pragma unroll
    for (int t = 0; t < 4; ++t){
      #pragma unroll
      for (int r = 0; r < 4; ++r){
        float p = __expf(sacc[t][r] * SC - mnew[r]);
        psum[r] += p;
        int q = lg*4 + r, key = t*16 + lr;
        int ch = (key >> 3) ^ (q & 7);
        Ps[wid][q*64 + ch*8 + (key & 7)] = (h16)p;
      }
    }
    #pragma unroll
    for (int r = 0; r < 4; ++r){
      #pragma unroll
      for (int off = 1; off < 16; off <<= 1) psum[r] += __shfl_xor(psum[r], off);
      l_run[r] = l_run[r] * c[r] + psum[r];
      m_run[r] = mnew[r];
    }
    #pragma unroll
    for (int dt = 0; dt < 12; ++dt){
      f32x4 o = oacc[dt];
      o[0] *= c[0]; o[1] *= c[1]; o[2] *= c[2]; o[3] *= c[3];
      oacc[dt] = o;
    }
    asm volatile("s_waitcnt lgkmcnt(0)" ::: "memory");  // P writes visible to own wave
    // O += P @ V  (V from VT slice: rows d, key-contiguous)
    #pragma unroll
    for (int kk = 0; kk < 2; ++kk){
      int ch = (kk*4 + lg) ^ (lr & 7);
      half8v pf = *(const half8v*)&Ps[wid][lr*64 + ch*8];
      #pragma unroll
      for (int dt = 0; dt < 12; ++dt){
        int drow = dt*16 + lr;
        int vch = (kk*4 + lg) ^ (drow & 7);
        half8v vf = *(const half8v*)&Vs[cur][drow*64 + vch*8];
        oacc[dt] = __builtin_amdgcn_mfma_f32_16x16x32_f16(pf, vf, oacc[dt], 0, 0, 0);
      }
    }
    __syncthreads();
  }
  float inv[4];
  #pragma unroll
  for (int r = 0; r < 4; ++r) inv[r] = 1.0f / l_run[r];
  h16* Og = Op + (size_t)b*NSEQ*DD + h*HDIM;
  #pragma unroll
  for (int dt = 0; dt < 12; ++dt){
    #pragma unroll
    for (int r = 0; r < 4; ++r){
      int q = q0 + wid*16 + lg*4 + r;
      Og[(size_t)q*DD + dt*16 + lr] = (h16)(oacc[dt][r] * inv[r]);
    }
  }
}

// ---------------- GAT helpers ----------------
__global__ __launch_bounds__(128) void k_rowdot(const h16* __restrict__ h,
    const float* __restrict__ aw, float* __restrict__ sj){
  __shared__ float red[2];
  int row = blockIdx.x, tid = threadIdx.x;
  float s = 0.f;
  if (tid < 96){
    half8v v = *(const half8v*)(h + (size_t)row * DD + tid*8);
    #pragma unroll
    for (int j = 0; j < 8; ++j) s += (float)v[j] * aw[tid*8 + j];
  }
  s = wave_sum(s);
  if ((tid & 63) == 0) red[tid >> 6] = s;
  __syncthreads();
  if (tid == 0) sj[row] = red[0] + red[1];
}

__global__ __launch_bounds__(256) void k_softmax1024(const float* __restrict__ x,
    float* __restrict__ y){
  __shared__ float red[4];
  int b = blockIdx.x, tid = threadIdx.x;
  const float* ip = x + b * NSEQ;
  float v[4]; float mx = -1e30f;
  #pragma unroll
  for (int j = 0; j < 4; ++j){ v[j] = ip[j * 256 + tid]; mx = fmaxf(mx, v[j]); }
  mx = wave_max(mx);
  if ((tid & 63) == 0) red[tid >> 6] = mx;
  __syncthreads();
  mx = fmaxf(fmaxf(red[0], red[1]), fmaxf(red[2], red[3]));
  __syncthreads();
  float s = 0.f;
  #pragma unroll
  for (int j = 0; j < 4; ++j){ v[j] = __expf(v[j] - mx); s += v[j]; }
  s = wave_sum(s);
  if ((tid & 63) == 0) red[tid >> 6] = s;
  __syncthreads();
  s = red[0] + red[1] + red[2] + red[3];
  float inv = 1.0f / s;
  #pragma unroll
  for (int j = 0; j < 4; ++j) y[b * NSEQ + j * 256 + tid] = v[j] * inv;
}

__global__ __launch_bounds__(256) void k_ctx1(const float* __restrict__ alpha,
    const h16* __restrict__ h, float* __restrict__ part){
  int d = blockIdx.x * 256 + threadIdx.x;
  int b = blockIdx.y, pc = blockIdx.z;
  if (d >= DD) return;
  float acc = 0.f;
  const h16* hp = h + ((size_t)b * NSEQ + pc * 64) * DD + d;
  const float* ap = alpha + b * NSEQ + pc * 64;
  #pragma unroll 4
  for (int j = 0; j < 64; ++j) acc += ap[j] * (float)hp[(size_t)j * DD];
  part[(size_t)(b * 16 + pc) * DD + d] = acc;
}
__global__ __launch_bounds__(256) void k_ctx2(const float* __restrict__ part,
    float scale, float* __restrict__ ctx){
  int d = blockIdx.x * 256 + threadIdx.x;
  int b = blockIdx.y;
  if (d >= DD) return;
  float acc = 0.f;
  #pragma unroll
  for (int p = 0; p < 16; ++p) acc += part[(size_t)(b * 16 + p) * DD + d];
  ctx[b * DD + d] = acc * scale;
}

__global__ __launch_bounds__(256) void k_pool1(const float* __restrict__ x,
    float* __restrict__ part){
  int d = blockIdx.x * 256 + threadIdx.x;
  int b = blockIdx.y, pc = blockIdx.z;
  if (d >= DD) return;
  float acc = 0.f;
  const float* xp = x + ((size_t)b * NSEQ + pc * 64) * DD + d;
  #pragma unroll 4
  for (int j = 0; j < 64; ++j) acc += xp[(size_t)j * DD];
  part[(size_t)(b * 16 + pc) * DD + d] = acc;
}

__global__ __launch_bounds__(128) void k_clf(const float* __restrict__ pooled,
    const float* __restrict__ w1, const float* __restrict__ b1,
    const float* __restrict__ w2, const float* __restrict__ b2,
    float* __restrict__ out){
  __shared__ float pl[DD];
  __shared__ float h1[128];
  int b = blockIdx.x, tid = threadIdx.x;
  #pragma unroll
  for (int j = 0; j < 6; ++j) pl[j * 128 + tid] = pooled[b * DD + j * 128 + tid];
  __syncthreads();
  float acc = b1[tid];
  const float* wp = w1 + (size_t)tid * DD;
  for (int d = 0; d < DD; ++d) acc += pl[d] * wp[d];
  h1[tid] = gelu_f(acc);
  __syncthreads();
  if (tid < 2){
    float o = b2[tid];
    const float* w2p = w2 + tid * 128;
    for (int c = 0; c < 128; ++c) o += h1[c] * w2p[c];
    out[b * 2 + tid] = o;
  }
}

// =========================== launcher ===========================
static void gemmN(hipStream_t s, const h16* A, const h16* W, int M, int N, int K,
                  int lda, int ldw, int ldc, int Z,
                  long long sAh, long long sAl, long long sWh, long long sWl,
                  long long sCh, long long sCl, int bzs,
                  const float* bias, const float* sc, const float* off,
                  const h16* addh, float* outf, h16* outh){
  dim3 g(N/64, M/128, Z);
  k_gemm_h<64><<<g, 256, 0, s>>>(A, W, sAh, sAl, sWh, sWl, sCh, sCl,
                                 lda, ldw, ldc, K, bzs, bias, sc, off, addh, outf, outh);
}

extern "C" void kernel_launch(void* const* d_in, const int* in_sizes, int n_in,
                              void* d_out, int out_size, void* d_ws, size_t ws_size,
                              hipStream_t stream){
  (void)in_sizes; (void)n_in; (void)out_size;
  const float* w2v      = (const float*)d_in[0];
  const float* cqcc     = (const float*)d_in[1];
  const float* conv1_w  = (const float*)d_in[2];
  const float* conv1_b  = (const float*)d_in[3];
  const float* bn1_g    = (const float*)d_in[4];
  const float* bn1_b    = (const float*)d_in[5];
  const float* bn1_m    = (const float*)d_in[6];
  const float* bn1_v    = (const float*)d_in[7];
  const float* conv2_w  = (const float*)d_in[8];
  const float* conv2_b  = (const float*)d_in[9];
  const float* bn2_g    = (const float*)d_in[10];
  const float* bn2_b    = (const float*)d_in[11];
  const float* bn2_m    = (const float*)d_in[12];
  const float* bn2_v    = (const float*)d_in[13];
  const float* pos_embed= (const float*)d_in[14];
  const float* lnq_g    = (const float*)d_in[15];
  const float* lnq_b    = (const float*)d_in[16];
  const float* lnkv_g   = (const float*)d_in[17];
  const float* lnkv_b   = (const float*)d_in[18];
  const float* a1_in_w  = (const float*)d_in[19];
  const float* a1_in_b  = (const float*)d_in[20];
  const float* a1_out_w = (const float*)d_in[21];
  const float* a1_out_b = (const float*)d_in[22];
  const float* a2_in_w  = (const float*)d_in[23];
  const float* a2_in_b  = (const float*)d_in[24];
  const float* a2_out_w = (const float*)d_in[25];
  const float* a2_out_b = (const float*)d_in[26];
  const float* gat_fc_w = (const float*)d_in[27];
  const float* gat_fc_b = (const float*)d_in[28];
  const float* gat_a_w  = (const float*)d_in[29];
  // d_in[30] gat_a_b: cancels in softmax over j — unused.
  const float* gln_g    = (const float*)d_in[31];
  const float* gln_b    = (const float*)d_in[32];
  const float* clf_w1   = (const float*)d_in[33];
  const float* clf_b1   = (const float*)d_in[34];
  const float* clf_w2   = (const float*)d_in[35];
  const float* clf_b2   = (const float*)d_in[36];

  char* wsp = (char*)d_ws;
  auto F = [&](size_t bytes){ char* p = wsp; wsp += (bytes + 255) & ~(size_t)255; return p; };
  float* Abuf  = (float*)F(25165824);   // cq f32 -> xb
  float* Bbuf  = (float*)F(25165824);   // wpl f32 -> xh
  h16* Lq_cq   = (h16*)F(12582912);     // also A2 (im2col), also Ob
  h16* Lkv_cq  = (h16*)F(12582912);     // also x1 (conv1 f32)
  h16* Lq_w    = (h16*)F(12582912);
  h16* Lkv_w   = (h16*)F(12582912);     // also o1h
  h16* Qh      = (h16*)F(12582912);     // ┐
  h16* KVh     = (h16*)F(25165824);     // ├ x2f f32 (49.2 MB) spans these
  h16* VT      = (h16*)F(12582912);     // ┘
  h16* w_a1in  = (h16*)F(3538944);
  h16* w_a1out = (h16*)F(1179648);
  h16* w_a2in  = (h16*)F(3538944);
  h16* w_a2out = (h16*)F(1179648);
  h16* w_gat   = (h16*)F(3538944);
  h16* w_c2    = (h16*)F(589824);
  float* scb   = (float*)F(3072);
  float* offb  = (float*)F(3072);
  float* sj    = (float*)F(32768);
  float* alpha = (float*)F(32768);
  float* ctxb  = (float*)F(24576);
  float* pooled= (float*)F(24576);
  float* partb = (float*)F(393216);
  if ((size_t)(wsp - (char*)d_ws) > ws_size) return;

  float* x1  = (float*)Lkv_cq;     // conv1 out f32 (8.2 MB)
  h16*   A2  = Lq_cq;              // im2col (12.3 MB)
  float* x2f = (float*)Qh;         // conv2 out f32, spans Qh+KVh+VT
  h16*   Ob  = Lq_cq;              // attention out
  h16*   o1h = Lkv_w;              // MHA1 result
  float* xb  = Abuf;               // GAT running state f32
  h16*   xh  = (h16*)Bbuf;         // f16 copy
  h16*   hh  = Qh;                 // GAT h

  const size_t S = (size_t)BBATCH * NSEQ * DD;
  const int EW = (int)((S + 255) / 256);
  const int NR = BBATCH * NSEQ;    // 8192

  // --- weight casts + bn prep ---
  k_cast<<<(1769472+255)/256, 256, 0, stream>>>(a1_in_w,  w_a1in,  1769472);
  k_cast<<<(589824+255)/256,  256, 0, stream>>>(a1_out_w, w_a1out, 589824);
  k_cast<<<(1769472+255)/256, 256, 0, stream>>>(a2_in_w,  w_a2in,  1769472);
  k_cast<<<(589824+255)/256,  256, 0, stream>>>(a2_out_w, w_a2out, 589824);
  k_cast<<<(1769472+255)/256, 256, 0, stream>>>(gat_fc_w, w_gat,   1769472);
  k_cast<<<(294912+255)/256,  256, 0, stream>>>(conv2_w,  w_c2,    294912);
  k_bnprep<<<3, 256, 0, stream>>>(conv2_b, bn2_g, bn2_b, bn2_m, bn2_v, scb, offb);

  // --- front-end convs ---
  k_conv1t<<<dim3(8, 4, BBATCH), 256, 0, stream>>>(cqcc, conv1_w, conv1_b,
      bn1_g, bn1_b, bn1_m, bn1_v, x1);
  k_im2col<<<(16000*384+255)/256, 256, 0, stream>>>(x1, A2);
  gemmN(stream, A2, w_c2, 16000, DD, 384, 384, 384, DD, 1,
        0,0,0,0,0,0, 0, nullptr, scb, offb, nullptr, x2f, nullptr);
  k_interp2<<<EW, 256, 0, stream>>>(x2f, pos_embed, Abuf);
  k_addpos<<<EW, 256, 0, stream>>>(w2v, pos_embed, Bbuf);

  // --- all four LN variants in two passes ---
  k_ln2two<<<NR, 256, 0, stream>>>(Abuf, lnq_g, lnq_b, Lq_cq, lnkv_g, lnkv_b, Lkv_cq);
  k_ln2two<<<NR, 256, 0, stream>>>(Bbuf, lnq_g, lnq_b, Lq_w,  lnkv_g, lnkv_b, Lkv_w);

  dim3 gflash(16, NH, BBATCH);

  // ================= MHA1: q = LNq(cq), kv = LNkv(w) =================
  gemmN(stream, Lq_cq, w_a1in, NR, DD, DD, DD, DD, DD, 1, 0,0,0,0,0,0, 0,
        a1_in_b, nullptr, nullptr, nullptr, nullptr, Qh);
  gemmN(stream, Lkv_w, w_a1in + 589824, NR, DD, DD, DD, DD, 1536, 2,
        0,0, 0,589824, 0,768, DD,
        a1_in_b + DD, nullptr, nullptr, nullptr, nullptr, KVh);
  k_trV<<<dim3(32, 6, 32), 256, 0, stream>>>(KVh + 768, 1536, VT);
  k_flash<<<gflash, 256, 0, stream>>>(Qh, KVh, VT, Ob);
  gemmN(stream, Ob, w_a1out, NR, DD, DD, DD, DD, DD, 1, 0,0,0,0,0,0, 0,
        a1_out_b, nullptr, nullptr, nullptr, nullptr, o1h);

  // ================= MHA2: q = LNq(w), kv = LNkv(cq) =================
  gemmN(stream, Lq_w, w_a2in, NR, DD, DD, DD, DD, DD, 1, 0,0,0,0,0,0, 0,
        a2_in_b, nullptr, nullptr, nullptr, nullptr, Qh);
  gemmN(stream, Lkv_cq, w_a2in + 589824, NR, DD, DD, DD, DD, 1536, 2,
        0,0, 0,589824, 0,768, DD,
        a2_in_b + DD, nullptr, nullptr, nullptr, nullptr, KVh);
  k_trV<<<dim3(32, 6, 32), 256, 0, stream>>>(KVh + 768, 1536, VT);
  k_flash<<<gflash, 256, 0, stream>>>(Qh, KVh, VT, Ob);
  gemmN(stream, Ob, w_a2out, NR, DD, DD, DD, DD, DD, 1, 0,0,0,0,0,0, 0,
        a2_out_b, nullptr, nullptr, o1h, xb, xh);

  // ================= GAT x3 (softmax over j collapses) =================
  for (int l = 0; l < 3; ++l){
    gemmN(stream, xh, w_gat + (size_t)l*589824, NR, DD, DD, DD, DD, DD, 1,
          0,0,0,0,0,0, 0, gat_fc_b + l*DD, nullptr, nullptr, nullptr, nullptr, hh);
    k_rowdot<<<NR, 128, 0, stream>>>(hh, gat_a_w + l*2*DD + DD, sj);
    k_softmax1024<<<BBATCH, 256, 0, stream>>>(sj, alpha);
    k_ctx1<<<dim3(3, BBATCH, 16), 256, 0, stream>>>(alpha, hh, partb);
    k_ctx2<<<dim3(3, BBATCH), 256, 0, stream>>>(partb, 1.0f, ctxb);
    k_ln2<<<NR, 256, 0, stream>>>(xb, ctxb, gln_g + l*DD, gln_b + l*DD, xb, xh);
  }

  k_pool1<<<dim3(3, BBATCH, 16), 256, 0, stream>>>(xb, partb);
  k_ctx2<<<dim3(3, BBATCH), 256, 0, stream>>>(partb, 1.0f/NSEQ, pooled);
  k_clf<<<BBATCH, 128, 0, stream>>>(pooled, clf_w1, clf_b1, clf_w2, clf_b2,
                                    (float*)d_out);
}